// Round 1
// baseline (1223.800 us; speedup 1.0000x reference)
//
#include <hip/hip_runtime.h>
#include <math.h>

#define B_   4
#define NQ_  300
#define DIM_ 256
#define H_   8
#define HD_  32
#define N_   4096
#define QT   3

// ---------------------------------------------------------------------------
// Generic 256-K GEMM: C[m,n] = (sum_k A[m,k]*W[k,n] + bias[n]) * scale
// kt_mode=1 writes K transposed as Kt[b, c, nk] with m = b*4096 + nk, c = n.
// ---------------------------------------------------------------------------
__global__ __launch_bounds__(256) void gemm256(
    const float* __restrict__ A, const float* __restrict__ W,
    const float* __restrict__ bias, float* __restrict__ C,
    int M, float scale, int kt_mode)
{
  __shared__ float As[16][68];
  __shared__ float Ws[16][68];
  const int tid = threadIdx.x;
  const int tx = tid & 15, ty = tid >> 4;
  const int bm = blockIdx.y * 64, bn = blockIdx.x * 64;
  float acc[4][4] = {};
  for (int k0 = 0; k0 < 256; k0 += 16) {
#pragma unroll
    for (int i = 0; i < 4; ++i) {
      int idx = tid + i * 256;
      int m = idx >> 4, k = idx & 15;
      int gm = bm + m;
      As[k][m] = (gm < M) ? A[gm * 256 + k0 + k] : 0.0f;
    }
#pragma unroll
    for (int i = 0; i < 4; ++i) {
      int idx = tid + i * 256;
      int k = idx >> 6, n = idx & 63;
      Ws[k][n] = W[(k0 + k) * 256 + bn + n];
    }
    __syncthreads();
#pragma unroll
    for (int k = 0; k < 16; ++k) {
      float a[4], w[4];
#pragma unroll
      for (int i = 0; i < 4; ++i) a[i] = As[k][ty * 4 + i];
#pragma unroll
      for (int j = 0; j < 4; ++j) w[j] = Ws[k][tx * 4 + j];
#pragma unroll
      for (int i = 0; i < 4; ++i)
#pragma unroll
        for (int j = 0; j < 4; ++j)
          acc[i][j] += a[i] * w[j];
    }
    __syncthreads();
  }
#pragma unroll
  for (int i = 0; i < 4; ++i) {
    int m = bm + ty * 4 + i;
    if (m >= M) continue;
#pragma unroll
    for (int j = 0; j < 4; ++j) {
      int n = bn + tx * 4 + j;
      float v = (acc[i][j] + bias[n]) * scale;
      if (kt_mode) {
        int b = m >> 12, nk = m & 4095;
        C[(size_t)b * (256 * 4096) + (size_t)n * 4096 + nk] = v;
      } else {
        C[(size_t)m * 256 + n] = v;
      }
    }
  }
}

// ---------------------------------------------------------------------------
// RPE MLP: per (b,q) block, per axis (grid.y: 0=x, 1=y).
// rpe[b,q,j,h] = sum_r relu(d0*W1[0,r] + d1*W1[1,r] + b1[r]) * W2[r,h]
// d0 = c - s/2 - pos_j, d1 = c + s/2 - pos_j, pos_j = (j+0.5)*16
// Kept fp32: rpe magnitudes reach ~1500; logit-space error must stay tiny.
// ---------------------------------------------------------------------------
__global__ __launch_bounds__(256) void rpe_kernel(
    const float* __restrict__ refpts,
    const float* __restrict__ W1x, const float* __restrict__ b1x, const float* __restrict__ W2x,
    const float* __restrict__ W1y, const float* __restrict__ b1y, const float* __restrict__ W2y,
    float* __restrict__ rpx, float* __restrict__ rpy)
{
  __shared__ float sW10[512], sW11[512], sB[512];
  __shared__ float sW2[512][8];
  __shared__ float sRed[64][4][8];
  const int tid = threadIdx.x;
  const int bq = blockIdx.x;
  const int axis = blockIdx.y;
  const float* W1 = axis ? W1y : W1x;
  const float* b1 = axis ? b1y : b1x;
  const float* W2 = axis ? W2y : W2x;
  float* out = axis ? rpy : rpx;

  for (int i = tid; i < 512; i += 256) {
    sW10[i] = W1[i];
    sW11[i] = W1[512 + i];
    sB[i] = b1[i];
#pragma unroll
    for (int hh = 0; hh < 8; ++hh) sW2[i][hh] = W2[i * 8 + hh];
  }
  const float c  = refpts[bq * 4 + axis];
  const float sz = refpts[bq * 4 + 2 + axis];
  __syncthreads();
  const int j = tid >> 2, rq = tid & 3;
  const float pos = (j + 0.5f) * 16.0f;
  const float d0 = c - 0.5f * sz - pos;
  const float d1 = c + 0.5f * sz - pos;
  float acc[8] = {};
  for (int rr = 0; rr < 128; ++rr) {
    int r = rq + rr * 4;                       // interleaved -> no LDS bank clash
    float hv = fmaxf(d0 * sW10[r] + d1 * sW11[r] + sB[r], 0.0f);
#pragma unroll
    for (int hh = 0; hh < 8; ++hh) acc[hh] += hv * sW2[r][hh];
  }
#pragma unroll
  for (int hh = 0; hh < 8; ++hh) sRed[j][rq][hh] = acc[hh];
  __syncthreads();
  for (int idx = tid; idx < 512; idx += 256) {
    int jj = idx >> 3, hh = idx & 7;
    out[(size_t)bq * 512 + jj * 8 + hh] =
        sRed[jj][0][hh] + sRed[jj][1][hh] + sRed[jj][2][hh] + sRed[jj][3][hh];
  }
}

// ---------------------------------------------------------------------------
// Fused attention: one block handles QT=3 queries for one (b,h).
// Phase 1: logits (QK + rpe_x[j] + rpe_y[i] + mask) into LDS, track max.
// Phase 2: exp + sum reduce. Phase 3: PV with d-coalesced V reads.
// ---------------------------------------------------------------------------
__global__ __launch_bounds__(256) void attn_kernel(
    const float* __restrict__ Q, const float* __restrict__ Kt,
    const float* __restrict__ V, const float* __restrict__ rpx,
    const float* __restrict__ rpy, const int* __restrict__ mask,
    float* __restrict__ X)
{
  __shared__ float sL[QT][N_];
  __shared__ float sq[QT][32];
  __shared__ float srx[QT][64];
  __shared__ float sry[QT][64];
  __shared__ float sredm[QT][4];
  __shared__ float sreds[QT][4];
  __shared__ float sPV[8][QT][32];

  const int tid = threadIdx.x;
  const int bid = blockIdx.x;
  const int qt = bid % (NQ_ / QT);
  const int h  = (bid / (NQ_ / QT)) % H_;
  const int b  = bid / ((NQ_ / QT) * H_);
  const int q0 = qt * QT;

  for (int i = tid; i < QT * 32; i += 256) {
    int qi = i >> 5, d = i & 31;
    sq[qi][d] = Q[(size_t)(b * NQ_ + q0 + qi) * DIM_ + h * HD_ + d];
  }
  for (int i = tid; i < QT * 64; i += 256) {
    int qi = i >> 6, j = i & 63;
    srx[qi][j] = rpx[(size_t)(b * NQ_ + q0 + qi) * 512 + j * 8 + h];
    sry[qi][j] = rpy[(size_t)(b * NQ_ + q0 + qi) * 512 + j * 8 + h];
  }
  __syncthreads();

  const float* kb = Kt + (size_t)b * (DIM_ * N_) + (size_t)(h * HD_) * N_;
  const int* mb = mask + b * N_;
  float lmax[QT];
#pragma unroll
  for (int qi = 0; qi < QT; ++qi) lmax[qi] = -1e30f;

  for (int n0 = 0; n0 < N_; n0 += 256) {
    const int n = n0 + tid;
    float acc[QT] = {};
#pragma unroll
    for (int d = 0; d < 32; ++d) {
      float kv = kb[(size_t)d * N_ + n];
#pragma unroll
      for (int qi = 0; qi < QT; ++qi) acc[qi] += sq[qi][d] * kv;
    }
    const float extra = -100.0f * (float)mb[n];
    const int j = n & 63, ii = n >> 6;
#pragma unroll
    for (int qi = 0; qi < QT; ++qi) {
      float v = acc[qi] + srx[qi][j] + sry[qi][ii] + extra;
      sL[qi][n] = v;
      lmax[qi] = fmaxf(lmax[qi], v);
    }
  }
#pragma unroll
  for (int qi = 0; qi < QT; ++qi) {
    float m = lmax[qi];
#pragma unroll
    for (int off = 32; off; off >>= 1) m = fmaxf(m, __shfl_down(m, off, 64));
    if ((tid & 63) == 0) sredm[qi][tid >> 6] = m;
  }
  __syncthreads();
  float mrow[QT], lsum[QT];
#pragma unroll
  for (int qi = 0; qi < QT; ++qi) {
    mrow[qi] = fmaxf(fmaxf(sredm[qi][0], sredm[qi][1]),
                     fmaxf(sredm[qi][2], sredm[qi][3]));
    lsum[qi] = 0.0f;
  }
  for (int n = tid; n < N_; n += 256) {
#pragma unroll
    for (int qi = 0; qi < QT; ++qi) {
      float p = __expf(sL[qi][n] - mrow[qi]);
      sL[qi][n] = p;
      lsum[qi] += p;
    }
  }
#pragma unroll
  for (int qi = 0; qi < QT; ++qi) {
    float s = lsum[qi];
#pragma unroll
    for (int off = 32; off; off >>= 1) s += __shfl_down(s, off, 64);
    if ((tid & 63) == 0) sreds[qi][tid >> 6] = s;
  }
  __syncthreads();
  float denom[QT];
#pragma unroll
  for (int qi = 0; qi < QT; ++qi)
    denom[qi] = sreds[qi][0] + sreds[qi][1] + sreds[qi][2] + sreds[qi][3];

  const int d = tid & 31, s = tid >> 5;   // 8 n-slices x 32 dims
  const float* vb = V + (size_t)b * (N_ * DIM_) + h * HD_ + d;
  float acc[QT] = {};
  for (int n = s; n < N_; n += 8) {
    float vv = vb[(size_t)n * DIM_];
#pragma unroll
    for (int qi = 0; qi < QT; ++qi) acc[qi] += sL[qi][n] * vv;
  }
#pragma unroll
  for (int qi = 0; qi < QT; ++qi) sPV[s][qi][d] = acc[qi];
  __syncthreads();
  if (tid < QT * 32) {
    int qi = tid >> 5, dd = tid & 31;
    float r = 0.0f;
#pragma unroll
    for (int ss = 0; ss < 8; ++ss) r += sPV[ss][qi][dd];
    X[(size_t)(b * NQ_ + q0 + qi) * DIM_ + h * HD_ + dd] = r / denom[qi];
  }
}

// ---------------------------------------------------------------------------
extern "C" void kernel_launch(void* const* d_in, const int* in_sizes, int n_in,
                              void* d_out, int out_size, void* d_ws, size_t ws_size,
                              hipStream_t stream)
{
  const float* query  = (const float*)d_in[0];
  const float* refpts = (const float*)d_in[1];
  const float* kin    = (const float*)d_in[2];
  const float* vin    = (const float*)d_in[3];
  const int*   mask   = (const int*)d_in[5];
  const float* Wq = (const float*)d_in[6];
  const float* bq = (const float*)d_in[7];
  const float* Wk = (const float*)d_in[8];
  const float* bk = (const float*)d_in[9];
  const float* Wv = (const float*)d_in[10];
  const float* bv = (const float*)d_in[11];
  const float* Wp = (const float*)d_in[12];
  const float* bp = (const float*)d_in[13];
  const float* W1x = (const float*)d_in[14];
  const float* b1x = (const float*)d_in[15];
  const float* W2x = (const float*)d_in[16];
  const float* W1y = (const float*)d_in[17];
  const float* b1y = (const float*)d_in[18];
  const float* W2y = (const float*)d_in[19];

  float* ws  = (float*)d_ws;
  float* Q   = ws;                    // 1200*256      =   307200
  float* Kt  = Q   + 307200;          // 4*256*4096    =  4194304 (transposed)
  float* Vp  = Kt  + 4194304;         // 4*4096*256    =  4194304
  float* rpx = Vp  + 4194304;         // 4*300*64*8    =   614400
  float* rpy = rpx + 614400;          //                   614400
  float* X   = rpy + 614400;          //                   307200

  const float scale = 0.17677669529663687f;  // 32^-0.5

  hipLaunchKernelGGL(gemm256, dim3(4, 19),  dim3(256), 0, stream,
                     query, Wq, bq, Q, B_ * NQ_, scale, 0);
  hipLaunchKernelGGL(gemm256, dim3(4, 256), dim3(256), 0, stream,
                     kin, Wk, bk, Kt, B_ * N_, 1.0f, 1);
  hipLaunchKernelGGL(gemm256, dim3(4, 256), dim3(256), 0, stream,
                     vin, Wv, bv, Vp, B_ * N_, 1.0f, 0);
  hipLaunchKernelGGL(rpe_kernel, dim3(B_ * NQ_, 2), dim3(256), 0, stream,
                     refpts, W1x, b1x, W2x, W1y, b1y, W2y, rpx, rpy);
  hipLaunchKernelGGL(attn_kernel, dim3((NQ_ / QT) * H_ * B_), dim3(256), 0, stream,
                     Q, Kt, Vp, rpx, rpy, mask, X);
  hipLaunchKernelGGL(gemm256, dim3(4, 19),  dim3(256), 0, stream,
                     X, Wp, bp, (float*)d_out, B_ * NQ_, 1.0f, 0);
}

// Round 2
// 756.123 us; speedup vs baseline: 1.6185x; 1.6185x over previous
//
#include <hip/hip_runtime.h>
#include <math.h>

#define B_   4
#define NQ_  300
#define DIM_ 256
#define H_   8
#define HD_  32
#define N_   4096
#define QT   3

// ---------------------------------------------------------------------------
// Generic 256-K GEMM: C[m,n] = (sum_k A[m,k]*W[k,n] + bias[n]) * scale
// kt_mode=1 writes transposed as T[b, c, nk] with m = b*4096 + nk, c = n.
// Used for both Kt and Vt so attention reads are float4-contiguous along n.
// ---------------------------------------------------------------------------
__global__ __launch_bounds__(256) void gemm256(
    const float* __restrict__ A, const float* __restrict__ W,
    const float* __restrict__ bias, float* __restrict__ C,
    int M, float scale, int kt_mode)
{
  __shared__ float As[16][68];
  __shared__ float Ws[16][68];
  const int tid = threadIdx.x;
  const int tx = tid & 15, ty = tid >> 4;
  const int bm = blockIdx.y * 64, bn = blockIdx.x * 64;
  float acc[4][4] = {};
  for (int k0 = 0; k0 < 256; k0 += 16) {
#pragma unroll
    for (int i = 0; i < 4; ++i) {
      int idx = tid + i * 256;
      int m = idx >> 4, k = idx & 15;
      int gm = bm + m;
      As[k][m] = (gm < M) ? A[gm * 256 + k0 + k] : 0.0f;
    }
#pragma unroll
    for (int i = 0; i < 4; ++i) {
      int idx = tid + i * 256;
      int k = idx >> 6, n = idx & 63;
      Ws[k][n] = W[(k0 + k) * 256 + bn + n];
    }
    __syncthreads();
#pragma unroll
    for (int k = 0; k < 16; ++k) {
      float a[4], w[4];
#pragma unroll
      for (int i = 0; i < 4; ++i) a[i] = As[k][ty * 4 + i];
#pragma unroll
      for (int j = 0; j < 4; ++j) w[j] = Ws[k][tx * 4 + j];
#pragma unroll
      for (int i = 0; i < 4; ++i)
#pragma unroll
        for (int j = 0; j < 4; ++j)
          acc[i][j] += a[i] * w[j];
    }
    __syncthreads();
  }
#pragma unroll
  for (int i = 0; i < 4; ++i) {
    int m = bm + ty * 4 + i;
    if (m >= M) continue;
#pragma unroll
    for (int j = 0; j < 4; ++j) {
      int n = bn + tx * 4 + j;
      float v = (acc[i][j] + bias[n]) * scale;
      if (kt_mode) {
        int b = m >> 12, nk = m & 4095;
        C[(size_t)b * (256 * 4096) + (size_t)n * 4096 + nk] = v;
      } else {
        C[(size_t)m * 256 + n] = v;
      }
    }
  }
}

// ---------------------------------------------------------------------------
// RPE MLP: per (b,q) block, per axis (grid.y: 0=x, 1=y). Kept fp32: rpe
// magnitudes reach ~1500; logit-space error must stay tiny.
// ---------------------------------------------------------------------------
__global__ __launch_bounds__(256) void rpe_kernel(
    const float* __restrict__ refpts,
    const float* __restrict__ W1x, const float* __restrict__ b1x, const float* __restrict__ W2x,
    const float* __restrict__ W1y, const float* __restrict__ b1y, const float* __restrict__ W2y,
    float* __restrict__ rpx, float* __restrict__ rpy)
{
  __shared__ float sW10[512], sW11[512], sB[512];
  __shared__ float sW2[512][8];
  __shared__ float sRed[64][4][8];
  const int tid = threadIdx.x;
  const int bq = blockIdx.x;
  const int axis = blockIdx.y;
  const float* W1 = axis ? W1y : W1x;
  const float* b1 = axis ? b1y : b1x;
  const float* W2 = axis ? W2y : W2x;
  float* out = axis ? rpy : rpx;

  for (int i = tid; i < 512; i += 256) {
    sW10[i] = W1[i];
    sW11[i] = W1[512 + i];
    sB[i] = b1[i];
#pragma unroll
    for (int hh = 0; hh < 8; ++hh) sW2[i][hh] = W2[i * 8 + hh];
  }
  const float c  = refpts[bq * 4 + axis];
  const float sz = refpts[bq * 4 + 2 + axis];
  __syncthreads();
  const int j = tid >> 2, rq = tid & 3;
  const float pos = (j + 0.5f) * 16.0f;
  const float d0 = c - 0.5f * sz - pos;
  const float d1 = c + 0.5f * sz - pos;
  float acc[8] = {};
  for (int rr = 0; rr < 128; ++rr) {
    int r = rq + rr * 4;
    float hv = fmaxf(d0 * sW10[r] + d1 * sW11[r] + sB[r], 0.0f);
#pragma unroll
    for (int hh = 0; hh < 8; ++hh) acc[hh] += hv * sW2[r][hh];
  }
#pragma unroll
  for (int hh = 0; hh < 8; ++hh) sRed[j][rq][hh] = acc[hh];
  __syncthreads();
  for (int idx = tid; idx < 512; idx += 256) {
    int jj = idx >> 3, hh = idx & 7;
    out[(size_t)bq * 512 + jj * 8 + hh] =
        sRed[jj][0][hh] + sRed[jj][1][hh] + sRed[jj][2][hh] + sRed[jj][3][hh];
  }
}

// ---------------------------------------------------------------------------
// Fused attention, float4 everywhere. One block = QT=3 queries of one (b,h).
// Kt/Vt layout: [b][c=h*32+d][n] so n is the fast axis (float4 reads).
// ---------------------------------------------------------------------------
__global__ __launch_bounds__(256) void attn_kernel(
    const float* __restrict__ Q, const float* __restrict__ Kt,
    const float* __restrict__ Vt, const float* __restrict__ rpx,
    const float* __restrict__ rpy, const int* __restrict__ mask,
    float* __restrict__ X)
{
  __shared__ float4 sL[QT][N_ / 4];     // 48 KB logits/probs
  __shared__ float sq[QT][32];
  __shared__ float srx[QT][64];
  __shared__ float sry[QT][64];
  __shared__ float sredm[QT][4];
  __shared__ float sreds[QT][4];
  __shared__ float sPV[8][QT][32];

  const int tid = threadIdx.x;
  const int bid = blockIdx.x;
  const int qt = bid % (NQ_ / QT);
  const int h  = (bid / (NQ_ / QT)) % H_;
  const int b  = bid / ((NQ_ / QT) * H_);
  const int q0 = qt * QT;

  for (int i = tid; i < QT * 32; i += 256) {
    int qi = i >> 5, d = i & 31;
    sq[qi][d] = Q[(size_t)(b * NQ_ + q0 + qi) * DIM_ + h * HD_ + d];
  }
  for (int i = tid; i < QT * 64; i += 256) {
    int qi = i >> 6, j = i & 63;
    srx[qi][j] = rpx[(size_t)(b * NQ_ + q0 + qi) * 512 + j * 8 + h];
    sry[qi][j] = rpy[(size_t)(b * NQ_ + q0 + qi) * 512 + j * 8 + h];
  }
  __syncthreads();

  const float4* kb4 = (const float4*)(Kt + (size_t)b * (DIM_ * N_) +
                                      (size_t)(h * HD_) * N_);   // [32][1024]
  const int4* mb4 = (const int4*)(mask + b * N_);
  float lmax[QT];
#pragma unroll
  for (int qi = 0; qi < QT; ++qi) lmax[qi] = -1e30f;

  // ---- Phase 1: logits. 4 chunks x (256 threads x 4 keys) ----
  for (int c0 = 0; c0 < 4; ++c0) {
    const int n4 = c0 * 256 + tid;        // float4 index along n
    float4 a[QT];
#pragma unroll
    for (int qi = 0; qi < QT; ++qi) a[qi] = make_float4(0.f, 0.f, 0.f, 0.f);
#pragma unroll
    for (int d = 0; d < 32; ++d) {
      float4 kv = kb4[d * (N_ / 4) + n4];
#pragma unroll
      for (int qi = 0; qi < QT; ++qi) {
        float qv = sq[qi][d];
        a[qi].x += qv * kv.x; a[qi].y += qv * kv.y;
        a[qi].z += qv * kv.z; a[qi].w += qv * kv.w;
      }
    }
    int4 mm = mb4[n4];
    const int n = n4 * 4;
    const int ii = n >> 6;               // row (y)
    const int j4 = (n & 63) >> 2;        // 4-aligned col group
    float4 ex = make_float4(-100.f * mm.x, -100.f * mm.y,
                            -100.f * mm.z, -100.f * mm.w);
#pragma unroll
    for (int qi = 0; qi < QT; ++qi) {
      float4 rx = ((const float4*)&srx[qi][0])[j4];
      float ry = sry[qi][ii];
      float4 v;
      v.x = a[qi].x + rx.x + ry + ex.x;
      v.y = a[qi].y + rx.y + ry + ex.y;
      v.z = a[qi].z + rx.z + ry + ex.z;
      v.w = a[qi].w + rx.w + ry + ex.w;
      sL[qi][n4] = v;
      lmax[qi] = fmaxf(lmax[qi], fmaxf(fmaxf(v.x, v.y), fmaxf(v.z, v.w)));
    }
  }
#pragma unroll
  for (int qi = 0; qi < QT; ++qi) {
    float m = lmax[qi];
#pragma unroll
    for (int off = 32; off; off >>= 1) m = fmaxf(m, __shfl_down(m, off, 64));
    if ((tid & 63) == 0) sredm[qi][tid >> 6] = m;
  }
  __syncthreads();
  float mrow[QT], lsum[QT];
#pragma unroll
  for (int qi = 0; qi < QT; ++qi) {
    mrow[qi] = fmaxf(fmaxf(sredm[qi][0], sredm[qi][1]),
                     fmaxf(sredm[qi][2], sredm[qi][3]));
    lsum[qi] = 0.0f;
  }

  // ---- Phase 2: exp + sum (float4) ----
  for (int i = tid; i < N_ / 4; i += 256) {
#pragma unroll
    for (int qi = 0; qi < QT; ++qi) {
      float4 p = sL[qi][i];
      p.x = __expf(p.x - mrow[qi]);
      p.y = __expf(p.y - mrow[qi]);
      p.z = __expf(p.z - mrow[qi]);
      p.w = __expf(p.w - mrow[qi]);
      sL[qi][i] = p;
      lsum[qi] += p.x + p.y + p.z + p.w;
    }
  }
#pragma unroll
  for (int qi = 0; qi < QT; ++qi) {
    float s = lsum[qi];
#pragma unroll
    for (int off = 32; off; off >>= 1) s += __shfl_down(s, off, 64);
    if ((tid & 63) == 0) sreds[qi][tid >> 6] = s;
  }
  __syncthreads();
  float denom[QT];
#pragma unroll
  for (int qi = 0; qi < QT; ++qi)
    denom[qi] = sreds[qi][0] + sreds[qi][1] + sreds[qi][2] + sreds[qi][3];

  // ---- Phase 3: PV. d = tid>>3 (0..31), s = tid&7 (8 n-slices) ----
  const int d = tid >> 3, s = tid & 7;
  const float4* vb4 = (const float4*)(Vt + (size_t)b * (DIM_ * N_) +
                                      (size_t)(h * HD_ + d) * N_);
  float acc[QT] = {};
  for (int n4 = s; n4 < N_ / 4; n4 += 8) {
    float4 vv = vb4[n4];
#pragma unroll
    for (int qi = 0; qi < QT; ++qi) {
      float4 p = sL[qi][n4];
      acc[qi] += p.x * vv.x + p.y * vv.y + p.z * vv.z + p.w * vv.w;
    }
  }
#pragma unroll
  for (int qi = 0; qi < QT; ++qi) sPV[s][qi][d] = acc[qi];
  __syncthreads();
  if (tid < QT * 32) {
    int qi = tid >> 5, dd = tid & 31;
    float r = 0.0f;
#pragma unroll
    for (int ss = 0; ss < 8; ++ss) r += sPV[ss][qi][dd];
    X[(size_t)(b * NQ_ + q0 + qi) * DIM_ + h * HD_ + dd] = r / denom[qi];
  }
}

// ---------------------------------------------------------------------------
extern "C" void kernel_launch(void* const* d_in, const int* in_sizes, int n_in,
                              void* d_out, int out_size, void* d_ws, size_t ws_size,
                              hipStream_t stream)
{
  const float* query  = (const float*)d_in[0];
  const float* refpts = (const float*)d_in[1];
  const float* kin    = (const float*)d_in[2];
  const float* vin    = (const float*)d_in[3];
  const int*   mask   = (const int*)d_in[5];
  const float* Wq = (const float*)d_in[6];
  const float* bq = (const float*)d_in[7];
  const float* Wk = (const float*)d_in[8];
  const float* bk = (const float*)d_in[9];
  const float* Wv = (const float*)d_in[10];
  const float* bv = (const float*)d_in[11];
  const float* Wp = (const float*)d_in[12];
  const float* bp = (const float*)d_in[13];
  const float* W1x = (const float*)d_in[14];
  const float* b1x = (const float*)d_in[15];
  const float* W2x = (const float*)d_in[16];
  const float* W1y = (const float*)d_in[17];
  const float* b1y = (const float*)d_in[18];
  const float* W2y = (const float*)d_in[19];

  float* ws  = (float*)d_ws;
  float* Q   = ws;                    // 1200*256      =   307200
  float* Kt  = Q   + 307200;          // 4*256*4096    =  4194304 (transposed)
  float* Vt  = Kt  + 4194304;         // 4*256*4096    =  4194304 (transposed)
  float* rpx = Vt  + 4194304;         // 4*300*64*8    =   614400
  float* rpy = rpx + 614400;          //                   614400
  float* X   = rpy + 614400;          //                   307200

  const float scale = 0.17677669529663687f;  // 32^-0.5

  hipLaunchKernelGGL(gemm256, dim3(4, 19),  dim3(256), 0, stream,
                     query, Wq, bq, Q, B_ * NQ_, scale, 0);
  hipLaunchKernelGGL(gemm256, dim3(4, 256), dim3(256), 0, stream,
                     kin, Wk, bk, Kt, B_ * N_, 1.0f, 1);
  hipLaunchKernelGGL(gemm256, dim3(4, 256), dim3(256), 0, stream,
                     vin, Wv, bv, Vt, B_ * N_, 1.0f, 1);
  hipLaunchKernelGGL(rpe_kernel, dim3(B_ * NQ_, 2), dim3(256), 0, stream,
                     refpts, W1x, b1x, W2x, W1y, b1y, W2y, rpx, rpy);
  hipLaunchKernelGGL(attn_kernel, dim3((NQ_ / QT) * H_ * B_), dim3(256), 0, stream,
                     Q, Kt, Vt, rpx, rpy, mask, X);
  hipLaunchKernelGGL(gemm256, dim3(4, 19),  dim3(256), 0, stream,
                     X, Wp, bp, (float*)d_out, B_ * NQ_, 1.0f, 0);
}

// Round 4
// 362.498 us; speedup vs baseline: 3.3760x; 2.0859x over previous
//
#include <hip/hip_runtime.h>
#include <math.h>

#define B_   4
#define NQ_  300
#define DIM_ 256
#define H_   8
#define HD_  32
#define N_   4096

typedef _Float16 f16;
typedef f16   f16x8 __attribute__((ext_vector_type(8)));
typedef f16   f16x4 __attribute__((ext_vector_type(4)));
typedef float f32x4 __attribute__((ext_vector_type(4)));

// ---------------------------------------------------------------------------
// Generic 256-K GEMM: C = (A @ W + bias) * scale.
// mode 0: fp32 row-major [m][256]
// mode 1: f16 row-major [m][256]            (Q, K)
// mode 2: f16 channel-transposed [b][c][nk] (V; m = b*4096+nk, c = n)
// ---------------------------------------------------------------------------
__global__ __launch_bounds__(256) void gemm256(
    const float* __restrict__ A, const float* __restrict__ W,
    const float* __restrict__ bias, void* __restrict__ C,
    int M, float scale, int mode)
{
  __shared__ float As[16][68];
  __shared__ float Ws[16][68];
  const int tid = threadIdx.x;
  const int tx = tid & 15, ty = tid >> 4;
  const int bm = blockIdx.y * 64, bn = blockIdx.x * 64;
  float acc[4][4] = {};
  for (int k0 = 0; k0 < 256; k0 += 16) {
#pragma unroll
    for (int i = 0; i < 4; ++i) {
      int idx = tid + i * 256;
      int m = idx >> 4, k = idx & 15;
      int gm = bm + m;
      As[k][m] = (gm < M) ? A[gm * 256 + k0 + k] : 0.0f;
    }
#pragma unroll
    for (int i = 0; i < 4; ++i) {
      int idx = tid + i * 256;
      int k = idx >> 6, n = idx & 63;
      Ws[k][n] = W[(k0 + k) * 256 + bn + n];
    }
    __syncthreads();
#pragma unroll
    for (int k = 0; k < 16; ++k) {
      const float4 av = *(const float4*)&As[k][ty * 4];
      const float4 wv = *(const float4*)&Ws[k][tx * 4];
      const float a[4] = {av.x, av.y, av.z, av.w};
      const float w[4] = {wv.x, wv.y, wv.z, wv.w};
#pragma unroll
      for (int i = 0; i < 4; ++i)
#pragma unroll
        for (int j = 0; j < 4; ++j)
          acc[i][j] += a[i] * w[j];
    }
    __syncthreads();
  }
  if (mode == 0) {
    float* Cf = (float*)C;
#pragma unroll
    for (int i = 0; i < 4; ++i) {
      int m = bm + ty * 4 + i;
      if (m >= M) continue;
#pragma unroll
      for (int j = 0; j < 4; ++j) {
        int n = bn + tx * 4 + j;
        Cf[(size_t)m * 256 + n] = (acc[i][j] + bias[n]) * scale;
      }
    }
  } else if (mode == 1) {
    f16* Ch = (f16*)C;
#pragma unroll
    for (int i = 0; i < 4; ++i) {
      int m = bm + ty * 4 + i;
      if (m >= M) continue;
      f16x4 pk;
#pragma unroll
      for (int j = 0; j < 4; ++j)
        pk[j] = (f16)((acc[i][j] + bias[bn + tx * 4 + j]) * scale);
      *(f16x4*)(Ch + (size_t)m * 256 + bn + tx * 4) = pk;
    }
  } else {
    f16* Ch = (f16*)C;
    const int m0 = bm + ty * 4;
    const int b = m0 >> 12, nk = m0 & 4095;
#pragma unroll
    for (int j = 0; j < 4; ++j) {
      int n = bn + tx * 4 + j;
      f16x4 pk;
#pragma unroll
      for (int i = 0; i < 4; ++i)
        pk[i] = (f16)((acc[i][j] + bias[n]) * scale);
      *(f16x4*)(Ch + (size_t)b * (256 * 4096) + (size_t)n * 4096 + nk) = pk;
    }
  }
}

// ---------------------------------------------------------------------------
// RPE MLP (fp32; rpe magnitudes ~1500, must not round).
// ---------------------------------------------------------------------------
__global__ __launch_bounds__(256) void rpe_kernel(
    const float* __restrict__ refpts,
    const float* __restrict__ W1x, const float* __restrict__ b1x, const float* __restrict__ W2x,
    const float* __restrict__ W1y, const float* __restrict__ b1y, const float* __restrict__ W2y,
    float* __restrict__ rpx, float* __restrict__ rpy)
{
  __shared__ float sW10[512], sW11[512], sB[512];
  __shared__ float sW2[512][8];
  __shared__ float sRed[64][4][8];
  const int tid = threadIdx.x;
  const int bq = blockIdx.x;
  const int axis = blockIdx.y;
  const float* W1 = axis ? W1y : W1x;
  const float* b1 = axis ? b1y : b1x;
  const float* W2 = axis ? W2y : W2x;
  float* out = axis ? rpy : rpx;

  for (int i = tid; i < 512; i += 256) {
    sW10[i] = W1[i];
    sW11[i] = W1[512 + i];
    sB[i] = b1[i];
#pragma unroll
    for (int hh = 0; hh < 8; ++hh) sW2[i][hh] = W2[i * 8 + hh];
  }
  const float c  = refpts[bq * 4 + axis];
  const float sz = refpts[bq * 4 + 2 + axis];
  __syncthreads();
  const int j = tid >> 2, rq = tid & 3;
  const float pos = (j + 0.5f) * 16.0f;
  const float d0 = c - 0.5f * sz - pos;
  const float d1 = c + 0.5f * sz - pos;
  float acc[8] = {};
  for (int rr = 0; rr < 128; ++rr) {
    int r = rq + rr * 4;
    float hv = fmaxf(d0 * sW10[r] + d1 * sW11[r] + sB[r], 0.0f);
#pragma unroll
    for (int hh = 0; hh < 8; ++hh) acc[hh] += hv * sW2[r][hh];
  }
#pragma unroll
  for (int hh = 0; hh < 8; ++hh) sRed[j][rq][hh] = acc[hh];
  __syncthreads();
  for (int idx = tid; idx < 512; idx += 256) {
    int jj = idx >> 3, hh = idx & 7;
    out[(size_t)bq * 512 + jj * 8 + hh] =
        sRed[jj][0][hh] + sRed[jj][1][hh] + sRed[jj][2][hh] + sRed[jj][3][hh];
  }
}

// ---------------------------------------------------------------------------
// MFMA attention with EXACT branchless online softmax (log2 domain).
// Block = one (b,h), 32 queries (two 16-q tiles); wave = (q-tile, key-half).
//   S^T = mfma_16x16x32_f16(Kfrag, Qfrag)  C-layout: col=query, row=key
//   per 16-key chunk: cross-g max (2 shfl_xor), rescale O/l, p=exp2(s-m)<=1
//   O  += mfma_16x16x16f16(Vtfrag, Pfrag)  P^T C-rows == B-operand k-layout
// Halves merged via stored (m,l,O) with per-half exp2 rescale.
// ---------------------------------------------------------------------------
__global__ __launch_bounds__(256) void attn_mfma(
    const f16* __restrict__ Qf, const f16* __restrict__ Kf,
    const f16* __restrict__ Vtf, const float* __restrict__ rpx,
    const float* __restrict__ rpy, const int* __restrict__ mask,
    float* __restrict__ X)
{
  __shared__ float smask[N_];          // -100*log2e*mask
  __shared__ float srx[32][67];        // rpe_x * log2e
  __shared__ float sry[32][67];        // rpe_y * log2e
  __shared__ float omrg[2][8][64];
  __shared__ float lmrg[32];
  __shared__ float smrg[32];

  const int tid = threadIdx.x;
  const int lane = tid & 63;
  const int wv = tid >> 6;
  const int qb = blockIdx.x % 10;
  const int h  = (blockIdx.x / 10) % H_;
  const int b  = blockIdx.x / (10 * H_);
  const int q0 = qb * 32;
  const float L2E = 1.44269504f;

  {
    const int4* mm4 = (const int4*)(mask + b * N_);
    for (int i = tid; i < N_ / 4; i += 256) {
      int4 mm = mm4[i];
      smask[4 * i + 0] = -100.f * L2E * (float)mm.x;
      smask[4 * i + 1] = -100.f * L2E * (float)mm.y;
      smask[4 * i + 2] = -100.f * L2E * (float)mm.z;
      smask[4 * i + 3] = -100.f * L2E * (float)mm.w;
    }
  }
  for (int i = tid; i < 2048; i += 256) {
    int qq = i >> 6, j = i & 63;
    int qg = q0 + qq; if (qg > NQ_ - 1) qg = NQ_ - 1;
    size_t base = (size_t)(b * NQ_ + qg) * 512 + (size_t)j * 8 + h;
    srx[qq][j] = rpx[base] * L2E;
    sry[qq][j] = rpy[base] * L2E;
  }
  __syncthreads();

  const int qt = wv & 1, kh = wv >> 1;
  const int l15 = lane & 15, g = lane >> 4;
  const int qloc = qt * 16 + l15;
  const int qrow = q0 + qloc;
  const int qq = qrow > NQ_ - 1 ? NQ_ - 1 : qrow;

  const f16x8 qf = *(const f16x8*)(Qf + (size_t)(b * NQ_ + qq) * 256 + h * 32 + g * 8);

  f32x4 O0 = {0.f, 0.f, 0.f, 0.f}, O1 = {0.f, 0.f, 0.f, 0.f};
  float lacc = 0.f;
  float mrun = -1e30f;
  const f16* kb  = Kf + (size_t)b * N_ * 256 + h * 32 + g * 8;
  const f16* v0p = Vtf + (size_t)(b * 256 + h * 32 + l15) * N_ + g * 4;
  const f16* v1p = v0p + (size_t)16 * N_;

  const int kend = kh * 2048 + 2048;
  for (int k0 = kh * 2048; k0 < kend; k0 += 16) {
    f16x8 kf = *(const f16x8*)(kb + (size_t)(k0 + l15) * 256);
    f32x4 S = __builtin_amdgcn_mfma_f32_16x16x32_f16(
        kf, qf, (f32x4){0.f, 0.f, 0.f, 0.f}, 0, 0, 0);
    const float ry2 = sry[qloc][k0 >> 6];
    float s2[4];
    float cmax = -1e30f;
#pragma unroll
    for (int r = 0; r < 4; ++r) {
      int key = k0 + g * 4 + r;
      float t = srx[qloc][key & 63] + smask[key] + ry2;
      s2[r] = S[r] * L2E + t;
      cmax = fmaxf(cmax, s2[r]);
    }
    cmax = fmaxf(cmax, __shfl_xor(cmax, 16));
    cmax = fmaxf(cmax, __shfl_xor(cmax, 32));
    const float mnew = fmaxf(mrun, cmax);
    const float f = exp2f(mrun - mnew);
    mrun = mnew;
    lacc *= f;
    f16x4 pf;
#pragma unroll
    for (int r = 0; r < 4; ++r) {
      float pv = exp2f(s2[r] - mnew);
      lacc += pv;
      pf[r] = (f16)pv;
    }
#pragma unroll
    for (int r = 0; r < 4; ++r) { O0[r] *= f; O1[r] *= f; }
    f16x4 vf0 = *(const f16x4*)(v0p + k0);
    f16x4 vf1 = *(const f16x4*)(v1p + k0);
    O0 = __builtin_amdgcn_mfma_f32_16x16x16f16(vf0, pf, O0, 0, 0, 0);
    O1 = __builtin_amdgcn_mfma_f32_16x16x16f16(vf1, pf, O1, 0, 0, 0);
  }
  lacc += __shfl_xor(lacc, 16);
  lacc += __shfl_xor(lacc, 32);

  if (kh == 1) {
#pragma unroll
    for (int r = 0; r < 4; ++r) {
      omrg[qt][r][lane] = O0[r];
      omrg[qt][4 + r][lane] = O1[r];
    }
    if (lane < 16) {
      lmrg[qt * 16 + lane] = lacc;
      smrg[qt * 16 + lane] = mrun;
    }
  }
  __syncthreads();
  if (kh == 0) {
    const float m1 = smrg[qt * 16 + l15];
    const float l1 = lmrg[qt * 16 + l15];
    const float ms = fmaxf(mrun, m1);
    const float f0 = exp2f(mrun - ms);
    const float f1 = exp2f(m1 - ms);
    const float rl = 1.0f / (lacc * f0 + l1 * f1);
    if (qrow < NQ_) {
      float* xr = X + (size_t)(b * NQ_ + qrow) * 256 + h * 32;
#pragma unroll
      for (int r = 0; r < 4; ++r) {
        xr[g * 4 + r]      = (O0[r] * f0 + omrg[qt][r][lane] * f1) * rl;
        xr[16 + g * 4 + r] = (O1[r] * f0 + omrg[qt][4 + r][lane] * f1) * rl;
      }
    }
  }
}

// ---------------------------------------------------------------------------
extern "C" void kernel_launch(void* const* d_in, const int* in_sizes, int n_in,
                              void* d_out, int out_size, void* d_ws, size_t ws_size,
                              hipStream_t stream)
{
  const float* query  = (const float*)d_in[0];
  const float* refpts = (const float*)d_in[1];
  const float* kin    = (const float*)d_in[2];
  const float* vin    = (const float*)d_in[3];
  const int*   mask   = (const int*)d_in[5];
  const float* Wq = (const float*)d_in[6];
  const float* bq = (const float*)d_in[7];
  const float* Wk = (const float*)d_in[8];
  const float* bk = (const float*)d_in[9];
  const float* Wv = (const float*)d_in[10];
  const float* bv = (const float*)d_in[11];
  const float* Wp = (const float*)d_in[12];
  const float* bp = (const float*)d_in[13];
  const float* W1x = (const float*)d_in[14];
  const float* b1x = (const float*)d_in[15];
  const float* W2x = (const float*)d_in[16];
  const float* W1y = (const float*)d_in[17];
  const float* b1y = (const float*)d_in[18];
  const float* W2y = (const float*)d_in[19];

  char* wsb = (char*)d_ws;
  f16*   Qf    = (f16*)(wsb);                    //  1200*256 f16
  f16*   Kf    = (f16*)(wsb + 614400);           //  4*4096*256 f16
  f16*   Vtf   = (f16*)(wsb + 9003008);          //  4*256*4096 f16
  float* rpx   = (float*)(wsb + 17391616);       //  4*300*512 f32
  float* rpy   = (float*)(wsb + 19849216);
  float* X     = (float*)(wsb + 22306816);       //  1200*256 f32

  const float scale = 0.17677669529663687f;  // 32^-0.5

  hipLaunchKernelGGL(gemm256, dim3(4, 19),  dim3(256), 0, stream,
                     query, Wq, bq, Qf, B_ * NQ_, scale, 1);
  hipLaunchKernelGGL(gemm256, dim3(4, 256), dim3(256), 0, stream,
                     kin, Wk, bk, Kf, B_ * N_, 1.0f, 1);
  hipLaunchKernelGGL(gemm256, dim3(4, 256), dim3(256), 0, stream,
                     vin, Wv, bv, Vtf, B_ * N_, 1.0f, 2);
  hipLaunchKernelGGL(rpe_kernel, dim3(B_ * NQ_, 2), dim3(256), 0, stream,
                     refpts, W1x, b1x, W2x, W1y, b1y, W2y, rpx, rpy);
  hipLaunchKernelGGL(attn_mfma, dim3(B_ * H_ * 10), dim3(256), 0, stream,
                     Qf, Kf, Vtf, rpx, rpy, mask, X);
  hipLaunchKernelGGL(gemm256, dim3(4, 19),  dim3(256), 0, stream,
                     X, Wp, bp, d_out, B_ * NQ_, 1.0f, 0);
}

// Round 5
// 270.182 us; speedup vs baseline: 4.5295x; 1.3417x over previous
//
#include <hip/hip_runtime.h>
#include <math.h>

#define B_   4
#define NQ_  300
#define DIM_ 256
#define H_   8
#define HD_  32
#define N_   4096

typedef _Float16 f16;
typedef f16   f16x8 __attribute__((ext_vector_type(8)));
typedef f16   f16x4 __attribute__((ext_vector_type(4)));
typedef float f32x4 __attribute__((ext_vector_type(4)));

// ---------------------------------------------------------------------------
// MFMA GEMM: C = (A @ W + bias) * scale.  M x 256 x 256, f16 compute.
// Block: 256 thr, 64(m) x 64(n) tile. Wave wv: rows wv*16..+16, all 64 n.
// A: fp32 (a_f16=0) or f16 row-major (a_f16=1).
// mode 0: fp32 row-major out; 1: f16 row-major; 2: f16 [b][c=n][nk=m&4095].
// LDS rows padded to 40 f16 (80 B): 16B-aligned f16x8 reads, <=2-way banks.
// ---------------------------------------------------------------------------
__global__ __launch_bounds__(256) void gemm_mfma(
    const void* __restrict__ Ain, const float* __restrict__ W,
    const float* __restrict__ bias, void* __restrict__ C,
    int M, float scale, int a_f16, int mode)
{
  __shared__ f16 As[64][40];
  __shared__ f16 Wt[64][40];
  const int tid = threadIdx.x;
  const int lane = tid & 63;
  const int wv = tid >> 6;
  const int l15 = lane & 15, g = lane >> 4;
  const int bm = blockIdx.y * 64, bn = blockIdx.x * 64;

  const int arow = tid >> 2, akq = (tid & 3) * 8;   // A stage: 64 rows x 32 k
  const int wk = tid >> 3, wn = (tid & 7) * 8;      // W stage: 32 k x 64 n

  f32x4 acc[4];
#pragma unroll
  for (int nt = 0; nt < 4; ++nt) acc[nt] = (f32x4){0.f, 0.f, 0.f, 0.f};

  for (int k0 = 0; k0 < 256; k0 += 32) {
    {
      const int gm = bm + arow;
      f16x8 av;
      if (gm < M) {
        if (a_f16) {
          av = *(const f16x8*)((const f16*)Ain + (size_t)gm * 256 + k0 + akq);
        } else {
          const float* ap = (const float*)Ain + (size_t)gm * 256 + k0 + akq;
          float4 a0 = *(const float4*)ap;
          float4 a1 = *(const float4*)(ap + 4);
          av[0] = (f16)a0.x; av[1] = (f16)a0.y; av[2] = (f16)a0.z; av[3] = (f16)a0.w;
          av[4] = (f16)a1.x; av[5] = (f16)a1.y; av[6] = (f16)a1.z; av[7] = (f16)a1.w;
        }
      } else {
#pragma unroll
        for (int i = 0; i < 8; ++i) av[i] = (f16)0.f;
      }
      *(f16x8*)&As[arow][akq] = av;
    }
    {
      const float* wr = W + (size_t)(k0 + wk) * 256 + bn + wn;
      float4 w0 = *(const float4*)wr;
      float4 w1 = *(const float4*)(wr + 4);
      Wt[wn + 0][wk] = (f16)w0.x; Wt[wn + 1][wk] = (f16)w0.y;
      Wt[wn + 2][wk] = (f16)w0.z; Wt[wn + 3][wk] = (f16)w0.w;
      Wt[wn + 4][wk] = (f16)w1.x; Wt[wn + 5][wk] = (f16)w1.y;
      Wt[wn + 6][wk] = (f16)w1.z; Wt[wn + 7][wk] = (f16)w1.w;
    }
    __syncthreads();
    const f16x8 af = *(const f16x8*)&As[wv * 16 + l15][g * 8];
#pragma unroll
    for (int nt = 0; nt < 4; ++nt) {
      const f16x8 bf = *(const f16x8*)&Wt[nt * 16 + l15][g * 8];
      acc[nt] = __builtin_amdgcn_mfma_f32_16x16x32_f16(af, bf, acc[nt], 0, 0, 0);
    }
    __syncthreads();
  }

#pragma unroll
  for (int nt = 0; nt < 4; ++nt) {
    const int n = bn + nt * 16 + l15;
    const float bv = bias[n];
    if (mode == 2) {
      const int m0 = bm + wv * 16 + g * 4;
      const int bb = m0 >> 12, nk = m0 & 4095;
      f16x4 pk;
#pragma unroll
      for (int r = 0; r < 4; ++r) pk[r] = (f16)((acc[nt][r] + bv) * scale);
      *(f16x4*)((f16*)C + (size_t)bb * (256 * 4096) + (size_t)n * 4096 + nk) = pk;
    } else {
#pragma unroll
      for (int r = 0; r < 4; ++r) {
        const int m = bm + wv * 16 + g * 4 + r;
        if (m >= M) continue;
        const float v = (acc[nt][r] + bv) * scale;
        if (mode == 0) ((float*)C)[(size_t)m * 256 + n] = v;
        else           ((f16*)C)[(size_t)m * 256 + n] = (f16)v;
      }
    }
  }
}

// ---------------------------------------------------------------------------
// RPE MLP (fp32; rpe magnitudes ~1500, must not round).
// ---------------------------------------------------------------------------
__global__ __launch_bounds__(256) void rpe_kernel(
    const float* __restrict__ refpts,
    const float* __restrict__ W1x, const float* __restrict__ b1x, const float* __restrict__ W2x,
    const float* __restrict__ W1y, const float* __restrict__ b1y, const float* __restrict__ W2y,
    float* __restrict__ rpx, float* __restrict__ rpy)
{
  __shared__ float sW10[512], sW11[512], sB[512];
  __shared__ float sW2[512][8];
  __shared__ float sRed[64][4][8];
  const int tid = threadIdx.x;
  const int bq = blockIdx.x;
  const int axis = blockIdx.y;
  const float* W1 = axis ? W1y : W1x;
  const float* b1 = axis ? b1y : b1x;
  const float* W2 = axis ? W2y : W2x;
  float* out = axis ? rpy : rpx;

  for (int i = tid; i < 512; i += 256) {
    sW10[i] = W1[i];
    sW11[i] = W1[512 + i];
    sB[i] = b1[i];
#pragma unroll
    for (int hh = 0; hh < 8; ++hh) sW2[i][hh] = W2[i * 8 + hh];
  }
  const float c  = refpts[bq * 4 + axis];
  const float sz = refpts[bq * 4 + 2 + axis];
  __syncthreads();
  const int j = tid >> 2, rq = tid & 3;
  const float pos = (j + 0.5f) * 16.0f;
  const float d0 = c - 0.5f * sz - pos;
  const float d1 = c + 0.5f * sz - pos;
  float acc[8] = {};
  for (int rr = 0; rr < 128; ++rr) {
    int r = rq + rr * 4;
    float hv = fmaxf(d0 * sW10[r] + d1 * sW11[r] + sB[r], 0.0f);
#pragma unroll
    for (int hh = 0; hh < 8; ++hh) acc[hh] += hv * sW2[r][hh];
  }
#pragma unroll
  for (int hh = 0; hh < 8; ++hh) sRed[j][rq][hh] = acc[hh];
  __syncthreads();
  for (int idx = tid; idx < 512; idx += 256) {
    int jj = idx >> 3, hh = idx & 7;
    out[(size_t)bq * 512 + jj * 8 + hh] =
        sRed[jj][0][hh] + sRed[jj][1][hh] + sRed[jj][2][hh] + sRed[jj][3][hh];
  }
}

// ---------------------------------------------------------------------------
// MFMA attention, exact online softmax (log2 domain), 8-wave split.
// Block = one (b,h,16q); wave kh handles keys [kh*512, kh*512+512).
// Explicit next-chunk K/V prefetch overlaps VMEM with the softmax chain.
// 8 partials (m,l,O) merged through LDS by wave 0. X written f16.
// ---------------------------------------------------------------------------
__global__ __launch_bounds__(512) void attn_mfma(
    const f16* __restrict__ Qf, const f16* __restrict__ Kf,
    const f16* __restrict__ Vtf, const float* __restrict__ rpx,
    const float* __restrict__ rpy, const int* __restrict__ mask,
    f16* __restrict__ X)
{
  __shared__ float smask[N_];          // -100*log2e*mask
  __shared__ float srx[16][67];        // rpe_x * log2e
  __shared__ float sry[16][67];        // rpe_y * log2e
  __shared__ float mO[7][8][64];
  __shared__ float mlm[7][16];
  __shared__ float mll[7][16];

  const int tid = threadIdx.x;
  const int lane = tid & 63;
  const int kh = tid >> 6;
  const int qb = blockIdx.x % 20;
  const int h  = (blockIdx.x / 20) % H_;
  const int b  = blockIdx.x / (20 * H_);
  const int q0 = qb * 16;
  const float L2E = 1.44269504f;

  {
    const int4* mm4 = (const int4*)(mask + b * N_);
    for (int i = tid; i < N_ / 4; i += 512) {
      int4 mm = mm4[i];
      smask[4 * i + 0] = -100.f * L2E * (float)mm.x;
      smask[4 * i + 1] = -100.f * L2E * (float)mm.y;
      smask[4 * i + 2] = -100.f * L2E * (float)mm.z;
      smask[4 * i + 3] = -100.f * L2E * (float)mm.w;
    }
  }
  for (int i = tid; i < 1024; i += 512) {
    int qq = i >> 6, j = i & 63;
    int qg = q0 + qq; if (qg > NQ_ - 1) qg = NQ_ - 1;
    size_t base = (size_t)(b * NQ_ + qg) * 512 + (size_t)j * 8 + h;
    srx[qq][j] = rpx[base] * L2E;
    sry[qq][j] = rpy[base] * L2E;
  }
  __syncthreads();

  const int l15 = lane & 15, g = lane >> 4;
  const int qrow = q0 + l15;
  const int qq = qrow > NQ_ - 1 ? NQ_ - 1 : qrow;

  const f16x8 qf = *(const f16x8*)(Qf + (size_t)(b * NQ_ + qq) * 256 + h * 32 + g * 8);

  f32x4 O0 = {0.f, 0.f, 0.f, 0.f}, O1 = {0.f, 0.f, 0.f, 0.f};
  float lacc = 0.f;
  float mrun = -1e30f;
  const f16* kb  = Kf + (size_t)b * N_ * 256 + h * 32 + g * 8;
  const f16* v0p = Vtf + (size_t)(b * 256 + h * 32 + l15) * N_ + g * 4;
  const f16* v1p = v0p + (size_t)16 * N_;

  auto process = [&](const f16x8 kf_, const f16x4 vf0_, const f16x4 vf1_, int k0_) {
    f32x4 S = __builtin_amdgcn_mfma_f32_16x16x32_f16(
        kf_, qf, (f32x4){0.f, 0.f, 0.f, 0.f}, 0, 0, 0);
    const float ry2 = sry[l15][k0_ >> 6];
    float s2[4];
    float cmax = -1e30f;
#pragma unroll
    for (int r = 0; r < 4; ++r) {
      int key = k0_ + g * 4 + r;
      float t = srx[l15][key & 63] + smask[key] + ry2;
      s2[r] = S[r] * L2E + t;
      cmax = fmaxf(cmax, s2[r]);
    }
    cmax = fmaxf(cmax, __shfl_xor(cmax, 16));
    cmax = fmaxf(cmax, __shfl_xor(cmax, 32));
    const float mnew = fmaxf(mrun, cmax);
    const float f = exp2f(mrun - mnew);
    mrun = mnew;
    lacc *= f;
    f16x4 pf;
#pragma unroll
    for (int r = 0; r < 4; ++r) {
      float pv = exp2f(s2[r] - mnew);
      lacc += pv;
      pf[r] = (f16)pv;
    }
#pragma unroll
    for (int r = 0; r < 4; ++r) { O0[r] *= f; O1[r] *= f; }
    O0 = __builtin_amdgcn_mfma_f32_16x16x16f16(vf0_, pf, O0, 0, 0, 0);
    O1 = __builtin_amdgcn_mfma_f32_16x16x16f16(vf1_, pf, O1, 0, 0, 0);
  };

  int k0 = kh * 512;
  f16x8 kf  = *(const f16x8*)(kb + (size_t)(k0 + l15) * 256);
  f16x4 vf0 = *(const f16x4*)(v0p + k0);
  f16x4 vf1 = *(const f16x4*)(v1p + k0);
  for (int kc = 0; kc < 31; ++kc, k0 += 16) {
    f16x8 kfn  = *(const f16x8*)(kb + (size_t)(k0 + 16 + l15) * 256);
    f16x4 vf0n = *(const f16x4*)(v0p + k0 + 16);
    f16x4 vf1n = *(const f16x4*)(v1p + k0 + 16);
    process(kf, vf0, vf1, k0);
    kf = kfn; vf0 = vf0n; vf1 = vf1n;
  }
  process(kf, vf0, vf1, k0);

  lacc += __shfl_xor(lacc, 16);
  lacc += __shfl_xor(lacc, 32);

  if (kh > 0) {
#pragma unroll
    for (int r = 0; r < 4; ++r) {
      mO[kh - 1][r][lane] = O0[r];
      mO[kh - 1][4 + r][lane] = O1[r];
    }
    if (lane < 16) {
      mlm[kh - 1][lane] = mrun;
      mll[kh - 1][lane] = lacc;
    }
  }
  __syncthreads();
  if (kh == 0) {
    float ms = mrun;
#pragma unroll
    for (int w = 0; w < 7; ++w) ms = fmaxf(ms, mlm[w][l15]);
    const float f0 = exp2f(mrun - ms);
    float lt = lacc * f0;
    float fw[7];
#pragma unroll
    for (int w = 0; w < 7; ++w) {
      fw[w] = exp2f(mlm[w][l15] - ms);
      lt += mll[w][l15] * fw[w];
    }
    const float rl = 1.0f / lt;
    if (qrow < NQ_) {
      f16* xr = X + (size_t)(b * NQ_ + qrow) * 256 + h * 32;
      f16x4 p0, p1;
#pragma unroll
      for (int r = 0; r < 4; ++r) {
        float o0 = O0[r] * f0, o1 = O1[r] * f0;
#pragma unroll
        for (int w = 0; w < 7; ++w) {
          o0 += mO[w][r][lane] * fw[w];
          o1 += mO[w][4 + r][lane] * fw[w];
        }
        p0[r] = (f16)(o0 * rl);
        p1[r] = (f16)(o1 * rl);
      }
      *(f16x4*)(xr + g * 4) = p0;
      *(f16x4*)(xr + 16 + g * 4) = p1;
    }
  }
}

// ---------------------------------------------------------------------------
extern "C" void kernel_launch(void* const* d_in, const int* in_sizes, int n_in,
                              void* d_out, int out_size, void* d_ws, size_t ws_size,
                              hipStream_t stream)
{
  const float* query  = (const float*)d_in[0];
  const float* refpts = (const float*)d_in[1];
  const float* kin    = (const float*)d_in[2];
  const float* vin    = (const float*)d_in[3];
  const int*   mask   = (const int*)d_in[5];
  const float* Wq = (const float*)d_in[6];
  const float* bq = (const float*)d_in[7];
  const float* Wk = (const float*)d_in[8];
  const float* bk = (const float*)d_in[9];
  const float* Wv = (const float*)d_in[10];
  const float* bv = (const float*)d_in[11];
  const float* Wp = (const float*)d_in[12];
  const float* bp = (const float*)d_in[13];
  const float* W1x = (const float*)d_in[14];
  const float* b1x = (const float*)d_in[15];
  const float* W2x = (const float*)d_in[16];
  const float* W1y = (const float*)d_in[17];
  const float* b1y = (const float*)d_in[18];
  const float* W2y = (const float*)d_in[19];

  char* wsb = (char*)d_ws;
  f16*   Qf  = (f16*)(wsb);                 // 1216*256 f16   = 622592 B
  f16*   Kf  = (f16*)(wsb + 622592);        // 4*4096*256 f16 = 8388608 B
  f16*   Vtf = (f16*)(wsb + 9011200);       // 4*256*4096 f16 = 8388608 B
  float* rpx = (float*)(wsb + 17399808);    // 4*300*512 f32  = 2457600 B
  float* rpy = (float*)(wsb + 19857408);    // 2457600 B
  f16*   X   = (f16*)(wsb + 22315008);      // 1216*256 f16   = 622592 B

  const float scale = 0.17677669529663687f;  // 32^-0.5

  hipLaunchKernelGGL(gemm_mfma, dim3(4, 19),  dim3(256), 0, stream,
                     query, Wq, bq, Qf, B_ * NQ_, scale, 0, 1);
  hipLaunchKernelGGL(gemm_mfma, dim3(4, 256), dim3(256), 0, stream,
                     kin, Wk, bk, Kf, B_ * N_, 1.0f, 0, 1);
  hipLaunchKernelGGL(gemm_mfma, dim3(4, 256), dim3(256), 0, stream,
                     vin, Wv, bv, Vtf, B_ * N_, 1.0f, 0, 2);
  hipLaunchKernelGGL(rpe_kernel, dim3(B_ * NQ_, 2), dim3(256), 0, stream,
                     refpts, W1x, b1x, W2x, W1y, b1y, W2y, rpx, rpy);
  hipLaunchKernelGGL(attn_mfma, dim3(B_ * H_ * 20), dim3(512), 0, stream,
                     Qf, Kf, Vtf, rpx, rpy, mask, X);
  hipLaunchKernelGGL(gemm_mfma, dim3(4, 19),  dim3(256), 0, stream,
                     X, Wp, bp, d_out, B_ * NQ_, 1.0f, 1, 0);
}

// Round 6
// 242.311 us; speedup vs baseline: 5.0505x; 1.1150x over previous
//
#include <hip/hip_runtime.h>
#include <math.h>

#define B_   4
#define NQ_  300
#define DIM_ 256
#define H_   8
#define HD_  32
#define N_   4096

typedef _Float16 f16;
typedef f16   f16x8 __attribute__((ext_vector_type(8)));
typedef f16   f16x4 __attribute__((ext_vector_type(4)));
typedef float f32x4 __attribute__((ext_vector_type(4)));

// ---------------------------------------------------------------------------
// Weight prep: WT[z][n][k] = W_z[k][n] * (z==0 ? qscale : 1), f16.
// ---------------------------------------------------------------------------
__global__ __launch_bounds__(256) void prep_wt(
    const float* __restrict__ Wq, const float* __restrict__ Wk,
    const float* __restrict__ Wv, const float* __restrict__ Wp,
    f16* __restrict__ WT, float qscale)
{
  __shared__ float t[64][65];
  const int z = blockIdx.z;
  const float* W = z == 0 ? Wq : z == 1 ? Wk : z == 2 ? Wv : Wp;
  const float s = z == 0 ? qscale : 1.0f;
  f16* O = WT + (size_t)z * 65536;
  const int k0 = blockIdx.y * 64, n0 = blockIdx.x * 64;
  const int r = threadIdx.x >> 2, c0 = (threadIdx.x & 3) * 16;
#pragma unroll
  for (int c = 0; c < 16; c += 4) {
    float4 v = *(const float4*)(W + (size_t)(k0 + r) * 256 + n0 + c0 + c);
    t[r][c0 + c] = v.x; t[r][c0 + c + 1] = v.y;
    t[r][c0 + c + 2] = v.z; t[r][c0 + c + 3] = v.w;
  }
  __syncthreads();
  f16* orow = O + (size_t)(n0 + r) * 256 + k0 + c0;
#pragma unroll
  for (int c = 0; c < 16; c += 4) {
    f16x4 p;
    p[0] = (f16)(t[c0 + c + 0][r] * s);
    p[1] = (f16)(t[c0 + c + 1][r] * s);
    p[2] = (f16)(t[c0 + c + 2][r] * s);
    p[3] = (f16)(t[c0 + c + 3][r] * s);
    *(f16x4*)(orow + c) = p;
  }
}

// ---------------------------------------------------------------------------
// MFMA GEMM body: C = A @ (WT^T) + bias*scale.  WT is [n][k] f16.
// mode 0: fp32 row-major out; 1: f16 row-major; 2: f16 [b][c=n][nk=m&4095].
// ---------------------------------------------------------------------------
__device__ __forceinline__ void gemm_body(
    const void* __restrict__ Ain, const f16* __restrict__ WT,
    const float* __restrict__ bias, void* __restrict__ C,
    int M, float scale, int a_f16, int mode, int bm, int bn, int tid)
{
  __shared__ f16 As[64][40];
  __shared__ f16 Bs[64][40];
  const int lane = tid & 63;
  const int wv = tid >> 6;
  const int l15 = lane & 15, g = lane >> 4;
  const int arow = tid >> 2, akq = (tid & 3) * 8;

  f32x4 acc[4];
#pragma unroll
  for (int nt = 0; nt < 4; ++nt) acc[nt] = (f32x4){0.f, 0.f, 0.f, 0.f};

  for (int k0 = 0; k0 < 256; k0 += 32) {
    {
      const int gm = bm + arow;
      f16x8 av;
      if (gm < M) {
        if (a_f16) {
          av = *(const f16x8*)((const f16*)Ain + (size_t)gm * 256 + k0 + akq);
        } else {
          const float* ap = (const float*)Ain + (size_t)gm * 256 + k0 + akq;
          float4 a0 = *(const float4*)ap;
          float4 a1 = *(const float4*)(ap + 4);
          av[0] = (f16)a0.x; av[1] = (f16)a0.y; av[2] = (f16)a0.z; av[3] = (f16)a0.w;
          av[4] = (f16)a1.x; av[5] = (f16)a1.y; av[6] = (f16)a1.z; av[7] = (f16)a1.w;
        }
      } else {
#pragma unroll
        for (int i = 0; i < 8; ++i) av[i] = (f16)0.f;
      }
      *(f16x8*)&As[arow][akq] = av;
      *(f16x8*)&Bs[arow][akq] =
          *(const f16x8*)(WT + (size_t)(bn + arow) * 256 + k0 + akq);
    }
    __syncthreads();
    const f16x8 af = *(const f16x8*)&As[wv * 16 + l15][g * 8];
#pragma unroll
    for (int nt = 0; nt < 4; ++nt) {
      const f16x8 bf = *(const f16x8*)&Bs[nt * 16 + l15][g * 8];
      acc[nt] = __builtin_amdgcn_mfma_f32_16x16x32_f16(af, bf, acc[nt], 0, 0, 0);
    }
    __syncthreads();
  }

#pragma unroll
  for (int nt = 0; nt < 4; ++nt) {
    const int n = bn + nt * 16 + l15;
    const float bv = bias[n] * scale;
    if (mode == 2) {
      const int m0 = bm + wv * 16 + g * 4;
      const int bb = m0 >> 12, nk = m0 & 4095;
      f16x4 pk;
#pragma unroll
      for (int r = 0; r < 4; ++r) pk[r] = (f16)(acc[nt][r] + bv);
      *(f16x4*)((f16*)C + (size_t)bb * (256 * 4096) + (size_t)n * 4096 + nk) = pk;
    } else {
#pragma unroll
      for (int r = 0; r < 4; ++r) {
        const int m = bm + wv * 16 + g * 4 + r;
        if (m >= M) continue;
        const float v = acc[nt][r] + bv;
        if (mode == 0) ((float*)C)[(size_t)m * 256 + n] = v;
        else           ((f16*)C)[(size_t)m * 256 + n] = (f16)v;
      }
    }
  }
}

// z=0: Q (M=1200), z=1: K, z=2: V  — one launch for all three projections.
__global__ __launch_bounds__(256) void proj_qkv(
    const float* __restrict__ query, const float* __restrict__ kin,
    const float* __restrict__ vin, const f16* __restrict__ WT,
    const float* __restrict__ bq, const float* __restrict__ bk,
    const float* __restrict__ bv, f16* __restrict__ Qf,
    f16* __restrict__ Kf, f16* __restrict__ Vtf, float qscale)
{
  const int z = blockIdx.z;
  const int bm = blockIdx.y * 64, bn = blockIdx.x * 64;
  if (z == 0) {
    if (bm >= B_ * NQ_) return;
    gemm_body(query, WT, bq, Qf, B_ * NQ_, qscale, 0, 1, bm, bn, threadIdx.x);
  } else if (z == 1) {
    gemm_body(kin, WT + 65536, bk, Kf, B_ * N_, 1.0f, 0, 1, bm, bn, threadIdx.x);
  } else {
    gemm_body(vin, WT + 2 * 65536, bv, Vtf, B_ * N_, 1.0f, 0, 2, bm, bn, threadIdx.x);
  }
}

__global__ __launch_bounds__(256) void gemm_out(
    const f16* __restrict__ X, const f16* __restrict__ WT,
    const float* __restrict__ bp, float* __restrict__ out)
{
  gemm_body(X, WT + 3 * 65536, bp, out, B_ * NQ_, 1.0f, 1, 0,
            blockIdx.y * 64, blockIdx.x * 64, threadIdx.x);
}

// ---------------------------------------------------------------------------
// RPE MLP, fp32 (rpe ~±1500; must not round). lane = position j, wave owns a
// 128-wide r-slice; all weight reads wave-uniform -> scalar loads, no LDS.
// ---------------------------------------------------------------------------
__global__ __launch_bounds__(256) void rpe_kernel(
    const float* __restrict__ refpts,
    const float* __restrict__ W1x, const float* __restrict__ b1x, const float* __restrict__ W2x,
    const float* __restrict__ W1y, const float* __restrict__ b1y, const float* __restrict__ W2y,
    float* __restrict__ rpx, float* __restrict__ rpy)
{
  __shared__ float sRed[4][64][8];
  const int tid = threadIdx.x;
  const int lane = tid & 63;
  const int wv = __builtin_amdgcn_readfirstlane(tid >> 6);
  const int bq = blockIdx.x;
  const int axis = blockIdx.y;
  const float* W1 = axis ? W1y : W1x;
  const float* b1 = axis ? b1y : b1x;
  const float* W2 = axis ? W2y : W2x;
  float* out = axis ? rpy : rpx;

  const float c  = refpts[bq * 4 + axis];
  const float sz = refpts[bq * 4 + 2 + axis];
  const float pos = (lane + 0.5f) * 16.0f;
  const float d0 = c - 0.5f * sz - pos;
  const float d1 = c + 0.5f * sz - pos;
  float acc[8] = {};
  const int r0 = wv * 128;
#pragma unroll 4
  for (int i = 0; i < 128; ++i) {
    const int r = r0 + i;
    const float w10 = W1[r], w11 = W1[512 + r], bb = b1[r];
    const float hv = fmaxf(fmaf(d0, w10, fmaf(d1, w11, bb)), 0.0f);
    const float* w2r = W2 + r * 8;
#pragma unroll
    for (int hh = 0; hh < 8; ++hh) acc[hh] += hv * w2r[hh];
  }
#pragma unroll
  for (int hh = 0; hh < 8; ++hh) sRed[wv][lane][hh] = acc[hh];
  __syncthreads();
  for (int idx = tid; idx < 512; idx += 256) {
    const int jj = idx >> 3, hh = idx & 7;
    out[(size_t)bq * 512 + idx] =
        sRed[0][jj][hh] + sRed[1][jj][hh] + sRed[2][jj][hh] + sRed[3][jj][hh];
  }
}

// ---------------------------------------------------------------------------
// MFMA attention, exact online softmax, two-pass per 128-key sub-pass:
// pass A caches s2 (8 x f32x4) in regs (independent chunks: MFMA + 16 VALU),
// one cross-lane max + O-rescale per 128 keys; pass B: exp2 + PV MFMA.
// Block = (b,h,16q), 8 waves x 512 keys; partials merged through LDS.
// ---------------------------------------------------------------------------
__global__ __launch_bounds__(512) void attn_mfma(
    const f16* __restrict__ Qf, const f16* __restrict__ Kf,
    const f16* __restrict__ Vtf, const float* __restrict__ rpx,
    const float* __restrict__ rpy, const int* __restrict__ mask,
    f16* __restrict__ X)
{
  __shared__ float smask[N_];          // -100*log2e*mask
  __shared__ float srx[16][68];        // rpe_x * log2e
  __shared__ float sry[16][68];        // rpe_y * log2e
  __shared__ float mO[7][8][64];
  __shared__ float mlm[7][16];
  __shared__ float mll[7][16];

  const int tid = threadIdx.x;
  const int lane = tid & 63;
  const int kh = tid >> 6;
  const int qb = blockIdx.x % 20;
  const int h  = (blockIdx.x / 20) % H_;
  const int b  = blockIdx.x / (20 * H_);
  const int q0 = qb * 16;
  const float L2E = 1.44269504f;

  {
    const int4* mm4 = (const int4*)(mask + b * N_);
    for (int i = tid; i < N_ / 4; i += 512) {
      int4 mm = mm4[i];
      smask[4 * i + 0] = -100.f * L2E * (float)mm.x;
      smask[4 * i + 1] = -100.f * L2E * (float)mm.y;
      smask[4 * i + 2] = -100.f * L2E * (float)mm.z;
      smask[4 * i + 3] = -100.f * L2E * (float)mm.w;
    }
  }
  for (int i = tid; i < 1024; i += 512) {
    int qq = i >> 6, j = i & 63;
    int qg = q0 + qq; if (qg > NQ_ - 1) qg = NQ_ - 1;
    size_t base = (size_t)(b * NQ_ + qg) * 512 + (size_t)j * 8 + h;
    srx[qq][j] = rpx[base] * L2E;
    sry[qq][j] = rpy[base] * L2E;
  }
  __syncthreads();

  const int l15 = lane & 15, g = lane >> 4;
  const int qrow = q0 + l15;
  const int qq = qrow > NQ_ - 1 ? NQ_ - 1 : qrow;

  const f16x8 qf = *(const f16x8*)(Qf + (size_t)(b * NQ_ + qq) * 256 + h * 32 + g * 8);

  f32x4 O0 = {0.f, 0.f, 0.f, 0.f}, O1 = {0.f, 0.f, 0.f, 0.f};
  float lacc = 0.f;
  float mrun = -1e30f;
  const f16* kb  = Kf + (size_t)b * N_ * 256 + h * 32 + g * 8;
  const f16* v0p = Vtf + (size_t)(b * 256 + h * 32 + l15) * N_ + g * 4;
  const f16* v1p = v0p + (size_t)16 * N_;

  for (int sp = 0; sp < 4; ++sp) {
    const int kbase = kh * 512 + sp * 128;
    f32x4 s2c[8];
    float lmax = -1e30f;
#pragma unroll
    for (int cc = 0; cc < 8; ++cc) {
      const int k0 = kbase + cc * 16;
      f16x8 kf = *(const f16x8*)(kb + (size_t)(k0 + l15) * 256);
      f32x4 S = __builtin_amdgcn_mfma_f32_16x16x32_f16(
          kf, qf, (f32x4){0.f, 0.f, 0.f, 0.f}, 0, 0, 0);
      const float ry2 = sry[l15][k0 >> 6];
      const float4 rx = *(const float4*)&srx[l15][(k0 & 63) + g * 4];
      const float4 sm = *(const float4*)&smask[k0 + g * 4];
      f32x4 s2;
      s2[0] = fmaf(S[0], L2E, rx.x + sm.x + ry2);
      s2[1] = fmaf(S[1], L2E, rx.y + sm.y + ry2);
      s2[2] = fmaf(S[2], L2E, rx.z + sm.z + ry2);
      s2[3] = fmaf(S[3], L2E, rx.w + sm.w + ry2);
      lmax = fmaxf(lmax, fmaxf(fmaxf(s2[0], s2[1]), fmaxf(s2[2], s2[3])));
      s2c[cc] = s2;
    }
    lmax = fmaxf(lmax, __shfl_xor(lmax, 16));
    lmax = fmaxf(lmax, __shfl_xor(lmax, 32));
    const float mnew = fmaxf(mrun, lmax);
    const float f = exp2f(mrun - mnew);
    mrun = mnew;
    lacc *= f;
#pragma unroll
    for (int r = 0; r < 4; ++r) { O0[r] *= f; O1[r] *= f; }
#pragma unroll
    for (int cc = 0; cc < 8; ++cc) {
      const int k0 = kbase + cc * 16;
      f16x4 pf;
      float ls = 0.f;
#pragma unroll
      for (int r = 0; r < 4; ++r) {
        const float pv = exp2f(s2c[cc][r] - mrun);
        ls += pv;
        pf[r] = (f16)pv;
      }
      lacc += ls;
      const f16x4 vf0 = *(const f16x4*)(v0p + k0);
      const f16x4 vf1 = *(const f16x4*)(v1p + k0);
      O0 = __builtin_amdgcn_mfma_f32_16x16x16f16(vf0, pf, O0, 0, 0, 0);
      O1 = __builtin_amdgcn_mfma_f32_16x16x16f16(vf1, pf, O1, 0, 0, 0);
    }
  }

  lacc += __shfl_xor(lacc, 16);
  lacc += __shfl_xor(lacc, 32);

  if (kh > 0) {
#pragma unroll
    for (int r = 0; r < 4; ++r) {
      mO[kh - 1][r][lane] = O0[r];
      mO[kh - 1][4 + r][lane] = O1[r];
    }
    if (lane < 16) {
      mlm[kh - 1][lane] = mrun;
      mll[kh - 1][lane] = lacc;
    }
  }
  __syncthreads();
  if (kh == 0) {
    float ms = mrun;
#pragma unroll
    for (int w = 0; w < 7; ++w) ms = fmaxf(ms, mlm[w][l15]);
    const float f0 = exp2f(mrun - ms);
    float lt = lacc * f0;
    float fw[7];
#pragma unroll
    for (int w = 0; w < 7; ++w) {
      fw[w] = exp2f(mlm[w][l15] - ms);
      lt += mll[w][l15] * fw[w];
    }
    const float rl = 1.0f / lt;
    if (qrow < NQ_) {
      f16* xr = X + (size_t)(b * NQ_ + qrow) * 256 + h * 32;
      f16x4 p0, p1;
#pragma unroll
      for (int r = 0; r < 4; ++r) {
        float o0 = O0[r] * f0, o1 = O1[r] * f0;
#pragma unroll
        for (int w = 0; w < 7; ++w) {
          o0 += mO[w][r][lane] * fw[w];
          o1 += mO[w][4 + r][lane] * fw[w];
        }
        p0[r] = (f16)(o0 * rl);
        p1[r] = (f16)(o1 * rl);
      }
      *(f16x4*)(xr + g * 4) = p0;
      *(f16x4*)(xr + 16 + g * 4) = p1;
    }
  }
}

// ---------------------------------------------------------------------------
extern "C" void kernel_launch(void* const* d_in, const int* in_sizes, int n_in,
                              void* d_out, int out_size, void* d_ws, size_t ws_size,
                              hipStream_t stream)
{
  const float* query  = (const float*)d_in[0];
  const float* refpts = (const float*)d_in[1];
  const float* kin    = (const float*)d_in[2];
  const float* vin    = (const float*)d_in[3];
  const int*   mask   = (const int*)d_in[5];
  const float* Wq = (const float*)d_in[6];
  const float* bq = (const float*)d_in[7];
  const float* Wk = (const float*)d_in[8];
  const float* bk = (const float*)d_in[9];
  const float* Wv = (const float*)d_in[10];
  const float* bv = (const float*)d_in[11];
  const float* Wp = (const float*)d_in[12];
  const float* bp = (const float*)d_in[13];
  const float* W1x = (const float*)d_in[14];
  const float* b1x = (const float*)d_in[15];
  const float* W2x = (const float*)d_in[16];
  const float* W1y = (const float*)d_in[17];
  const float* b1y = (const float*)d_in[18];
  const float* W2y = (const float*)d_in[19];

  char* wsb = (char*)d_ws;
  f16*   Qf  = (f16*)(wsb);                 // 1216*256 f16   = 622592 B
  f16*   Kf  = (f16*)(wsb + 622592);        // 4*4096*256 f16 = 8388608 B
  f16*   Vtf = (f16*)(wsb + 9011200);       // 4*256*4096 f16 = 8388608 B
  float* rpx = (float*)(wsb + 17399808);    // 4*300*512 f32  = 2457600 B
  float* rpy = (float*)(wsb + 19857408);    // 2457600 B
  f16*   X   = (f16*)(wsb + 22315008);      // 1216*256 f16   = 622592 B
  f16*   WT  = (f16*)(wsb + 22937600);      // 4*256*256 f16  = 524288 B

  const float scale = 0.17677669529663687f;  // 32^-0.5

  hipLaunchKernelGGL(prep_wt, dim3(4, 4, 4), dim3(256), 0, stream,
                     Wq, Wk, Wv, Wp, WT, scale);
  hipLaunchKernelGGL(rpe_kernel, dim3(B_ * NQ_, 2), dim3(256), 0, stream,
                     refpts, W1x, b1x, W2x, W1y, b1y, W2y, rpx, rpy);
  hipLaunchKernelGGL(proj_qkv, dim3(4, 256, 3), dim3(256), 0, stream,
                     query, kin, vin, WT, bq, bk, bv, Qf, Kf, Vtf, scale);
  hipLaunchKernelGGL(attn_mfma, dim3(B_ * H_ * 20), dim3(512), 0, stream,
                     Qf, Kf, Vtf, rpx, rpy, mask, X);
  hipLaunchKernelGGL(gemm_out, dim3(4, 19), dim3(256), 0, stream,
                     X, WT, bp, (float*)d_out);
}

// Round 7
// 222.963 us; speedup vs baseline: 5.4888x; 1.0868x over previous
//
#include <hip/hip_runtime.h>
#include <math.h>

#define B_   4
#define NQ_  300
#define DIM_ 256
#define H_   8
#define HD_  32
#define N_   4096

typedef _Float16 f16;
typedef f16   f16x8 __attribute__((ext_vector_type(8)));
typedef f16   f16x4 __attribute__((ext_vector_type(4)));
typedef float f32x4 __attribute__((ext_vector_type(4)));

// ---------------------------------------------------------------------------
// Weight prep: WT[z][n][k] = W_z[k][n] * (z==0 ? qscale : 1), f16.
// ---------------------------------------------------------------------------
__global__ __launch_bounds__(256) void prep_wt(
    const float* __restrict__ Wq, const float* __restrict__ Wk,
    const float* __restrict__ Wv, const float* __restrict__ Wp,
    f16* __restrict__ WT, float qscale)
{
  __shared__ float t[64][65];
  const int z = blockIdx.z;
  const float* W = z == 0 ? Wq : z == 1 ? Wk : z == 2 ? Wv : Wp;
  const float s = z == 0 ? qscale : 1.0f;
  f16* O = WT + (size_t)z * 65536;
  const int k0 = blockIdx.y * 64, n0 = blockIdx.x * 64;
  const int r = threadIdx.x >> 2, c0 = (threadIdx.x & 3) * 16;
#pragma unroll
  for (int c = 0; c < 16; c += 4) {
    float4 v = *(const float4*)(W + (size_t)(k0 + r) * 256 + n0 + c0 + c);
    t[r][c0 + c] = v.x; t[r][c0 + c + 1] = v.y;
    t[r][c0 + c + 2] = v.z; t[r][c0 + c + 3] = v.w;
  }
  __syncthreads();
  f16* orow = O + (size_t)(n0 + r) * 256 + k0 + c0;
#pragma unroll
  for (int c = 0; c < 16; c += 4) {
    f16x4 p;
    p[0] = (f16)(t[c0 + c + 0][r] * s);
    p[1] = (f16)(t[c0 + c + 1][r] * s);
    p[2] = (f16)(t[c0 + c + 2][r] * s);
    p[3] = (f16)(t[c0 + c + 3][r] * s);
    *(f16x4*)(orow + c) = p;
  }
}

// ---------------------------------------------------------------------------
// MFMA GEMM body: C = A @ (WT^T) + bias*scale.  WT is [n][k] f16.
// mode 0: fp32 row-major out; 1: f16 row-major; 2: f16 [b][c=n][nk=m&4095].
// ---------------------------------------------------------------------------
__device__ __forceinline__ void gemm_body(
    const void* __restrict__ Ain, const f16* __restrict__ WT,
    const float* __restrict__ bias, void* __restrict__ C,
    int M, float scale, int a_f16, int mode, int bm, int bn, int tid)
{
  __shared__ f16 As[64][40];
  __shared__ f16 Bs[64][40];
  const int lane = tid & 63;
  const int wv = tid >> 6;
  const int l15 = lane & 15, g = lane >> 4;
  const int arow = tid >> 2, akq = (tid & 3) * 8;

  f32x4 acc[4];
#pragma unroll
  for (int nt = 0; nt < 4; ++nt) acc[nt] = (f32x4){0.f, 0.f, 0.f, 0.f};

  for (int k0 = 0; k0 < 256; k0 += 32) {
    {
      const int gm = bm + arow;
      f16x8 av;
      if (gm < M) {
        if (a_f16) {
          av = *(const f16x8*)((const f16*)Ain + (size_t)gm * 256 + k0 + akq);
        } else {
          const float* ap = (const float*)Ain + (size_t)gm * 256 + k0 + akq;
          float4 a0 = *(const float4*)ap;
          float4 a1 = *(const float4*)(ap + 4);
          av[0] = (f16)a0.x; av[1] = (f16)a0.y; av[2] = (f16)a0.z; av[3] = (f16)a0.w;
          av[4] = (f16)a1.x; av[5] = (f16)a1.y; av[6] = (f16)a1.z; av[7] = (f16)a1.w;
        }
      } else {
#pragma unroll
        for (int i = 0; i < 8; ++i) av[i] = (f16)0.f;
      }
      *(f16x8*)&As[arow][akq] = av;
      *(f16x8*)&Bs[arow][akq] =
          *(const f16x8*)(WT + (size_t)(bn + arow) * 256 + k0 + akq);
    }
    __syncthreads();
    const f16x8 af = *(const f16x8*)&As[wv * 16 + l15][g * 8];
#pragma unroll
    for (int nt = 0; nt < 4; ++nt) {
      const f16x8 bf = *(const f16x8*)&Bs[nt * 16 + l15][g * 8];
      acc[nt] = __builtin_amdgcn_mfma_f32_16x16x32_f16(af, bf, acc[nt], 0, 0, 0);
    }
    __syncthreads();
  }

#pragma unroll
  for (int nt = 0; nt < 4; ++nt) {
    const int n = bn + nt * 16 + l15;
    const float bv = bias[n] * scale;
    if (mode == 2) {
      const int m0 = bm + wv * 16 + g * 4;
      const int bb = m0 >> 12, nk = m0 & 4095;
      f16x4 pk;
#pragma unroll
      for (int r = 0; r < 4; ++r) pk[r] = (f16)(acc[nt][r] + bv);
      *(f16x4*)((f16*)C + (size_t)bb * (256 * 4096) + (size_t)n * 4096 + nk) = pk;
    } else {
#pragma unroll
      for (int r = 0; r < 4; ++r) {
        const int m = bm + wv * 16 + g * 4 + r;
        if (m >= M) continue;
        const float v = acc[nt][r] + bv;
        if (mode == 0) ((float*)C)[(size_t)m * 256 + n] = v;
        else           ((f16*)C)[(size_t)m * 256 + n] = (f16)v;
      }
    }
  }
}

// z=0: Q (M=1200), z=1: K, z=2: V  — one launch for all three projections.
__global__ __launch_bounds__(256) void proj_qkv(
    const float* __restrict__ query, const float* __restrict__ kin,
    const float* __restrict__ vin, const f16* __restrict__ WT,
    const float* __restrict__ bq, const float* __restrict__ bk,
    const float* __restrict__ bv, f16* __restrict__ Qf,
    f16* __restrict__ Kf, f16* __restrict__ Vtf, float qscale)
{
  const int z = blockIdx.z;
  const int bm = blockIdx.y * 64, bn = blockIdx.x * 64;
  if (z == 0) {
    if (bm >= B_ * NQ_) return;
    gemm_body(query, WT, bq, Qf, B_ * NQ_, qscale, 0, 1, bm, bn, threadIdx.x);
  } else if (z == 1) {
    gemm_body(kin, WT + 65536, bk, Kf, B_ * N_, 1.0f, 0, 1, bm, bn, threadIdx.x);
  } else {
    gemm_body(vin, WT + 2 * 65536, bv, Vtf, B_ * N_, 1.0f, 0, 2, bm, bn, threadIdx.x);
  }
}

__global__ __launch_bounds__(256) void gemm_out(
    const f16* __restrict__ X, const f16* __restrict__ WT,
    const float* __restrict__ bp, float* __restrict__ out)
{
  gemm_body(X, WT + 3 * 65536, bp, out, B_ * NQ_, 1.0f, 1, 0,
            blockIdx.y * 64, blockIdx.x * 64, threadIdx.x);
}

// ---------------------------------------------------------------------------
// RPE MLP, fp32 (rpe ~±1500; must not round). lane = position j, wave owns a
// 128-wide r-slice; all weight reads wave-uniform -> scalar loads, no LDS.
// ---------------------------------------------------------------------------
__global__ __launch_bounds__(256) void rpe_kernel(
    const float* __restrict__ refpts,
    const float* __restrict__ W1x, const float* __restrict__ b1x, const float* __restrict__ W2x,
    const float* __restrict__ W1y, const float* __restrict__ b1y, const float* __restrict__ W2y,
    float* __restrict__ rpx, float* __restrict__ rpy)
{
  __shared__ float sRed[4][64][8];
  const int tid = threadIdx.x;
  const int lane = tid & 63;
  const int wv = __builtin_amdgcn_readfirstlane(tid >> 6);
  const int bq = blockIdx.x;
  const int axis = blockIdx.y;
  const float* W1 = axis ? W1y : W1x;
  const float* b1 = axis ? b1y : b1x;
  const float* W2 = axis ? W2y : W2x;
  float* out = axis ? rpy : rpx;

  const float c  = refpts[bq * 4 + axis];
  const float sz = refpts[bq * 4 + 2 + axis];
  const float pos = (lane + 0.5f) * 16.0f;
  const float d0 = c - 0.5f * sz - pos;
  const float d1 = c + 0.5f * sz - pos;
  float acc[8] = {};
  const int r0 = wv * 128;
#pragma unroll 4
  for (int i = 0; i < 128; ++i) {
    const int r = r0 + i;
    const float w10 = W1[r], w11 = W1[512 + r], bb = b1[r];
    const float hv = fmaxf(fmaf(d0, w10, fmaf(d1, w11, bb)), 0.0f);
    const float* w2r = W2 + r * 8;
#pragma unroll
    for (int hh = 0; hh < 8; ++hh) acc[hh] += hv * w2r[hh];
  }
#pragma unroll
  for (int hh = 0; hh < 8; ++hh) sRed[wv][lane][hh] = acc[hh];
  __syncthreads();
  for (int idx = tid; idx < 512; idx += 256) {
    const int jj = idx >> 3, hh = idx & 7;
    out[(size_t)bq * 512 + idx] =
        sRed[0][jj][hh] + sRed[1][jj][hh] + sRed[2][jj][hh] + sRed[3][jj][hh];
  }
}

// ---------------------------------------------------------------------------
// MFMA attention. Block = (b,h,32q): two 16-q tiles per wave, 8 waves x 512
// keys. Per 64-key sub-pass: batch-load 4 K-chunks + 8 V-frags into register
// arrays (12 loads in flight), then QK MFMA + score fixup (both q-tiles share
// each K load), one cross-lane max/rescale, then exp2 + 4 PV MFMAs per chunk.
// Exact online softmax in log2 domain; 8 partials merged through LDS.
// ---------------------------------------------------------------------------
__global__ __launch_bounds__(512) void attn_mfma(
    const f16* __restrict__ Qf, const f16* __restrict__ Kf,
    const f16* __restrict__ Vtf, const float* __restrict__ rpx,
    const float* __restrict__ rpy, const int* __restrict__ mask,
    f16* __restrict__ X)
{
  __shared__ float smask[N_];          // -100*log2e*mask
  __shared__ float srx[32][68];        // rpe_x * log2e
  __shared__ float sry[32][68];        // rpe_y * log2e
  __shared__ float mO[7][2][8][64];
  __shared__ float mlm[7][32];
  __shared__ float mll[7][32];

  const int tid = threadIdx.x;
  const int lane = tid & 63;
  const int kh = tid >> 6;
  const int qg = blockIdx.x % 10;
  const int h  = (blockIdx.x / 10) % H_;
  const int b  = blockIdx.x / (10 * H_);
  const int q0 = qg * 32;
  const float L2E = 1.44269504f;

  {
    const int4* mm4 = (const int4*)(mask + b * N_);
    for (int i = tid; i < N_ / 4; i += 512) {
      int4 mm = mm4[i];
      smask[4 * i + 0] = -100.f * L2E * (float)mm.x;
      smask[4 * i + 1] = -100.f * L2E * (float)mm.y;
      smask[4 * i + 2] = -100.f * L2E * (float)mm.z;
      smask[4 * i + 3] = -100.f * L2E * (float)mm.w;
    }
  }
  for (int i = tid; i < 2048; i += 512) {
    int qq = i >> 6, j = i & 63;
    int qg2 = q0 + qq; if (qg2 > NQ_ - 1) qg2 = NQ_ - 1;
    size_t base = (size_t)(b * NQ_ + qg2) * 512 + (size_t)j * 8 + h;
    srx[qq][j] = rpx[base] * L2E;
    sry[qq][j] = rpy[base] * L2E;
  }
  __syncthreads();

  const int l15 = lane & 15, g = lane >> 4;
  const int qrow0 = q0 + l15;
  const int qrow1 = q0 + 16 + l15;
  const int qa = qrow0 > NQ_ - 1 ? NQ_ - 1 : qrow0;
  const int qbq = qrow1 > NQ_ - 1 ? NQ_ - 1 : qrow1;

  const f16x8 qf0 = *(const f16x8*)(Qf + (size_t)(b * NQ_ + qa) * 256 + h * 32 + g * 8);
  const f16x8 qf1 = *(const f16x8*)(Qf + (size_t)(b * NQ_ + qbq) * 256 + h * 32 + g * 8);

  f32x4 O00 = {0.f,0.f,0.f,0.f}, O01 = {0.f,0.f,0.f,0.f};
  f32x4 O10 = {0.f,0.f,0.f,0.f}, O11 = {0.f,0.f,0.f,0.f};
  float lacc0 = 0.f, lacc1 = 0.f;
  float mrun0 = -1e30f, mrun1 = -1e30f;
  const f16* kb  = Kf + (size_t)b * N_ * 256 + h * 32 + g * 8;
  const f16* v0p = Vtf + (size_t)(b * 256 + h * 32 + l15) * N_ + g * 4;
  const f16* v1p = v0p + (size_t)16 * N_;

  for (int sp = 0; sp < 8; ++sp) {
    const int kbase = kh * 512 + sp * 64;
    // ---- batch loads: 12 VMEM in flight ----
    f16x8 kf[4];
    f16x4 va[4], vb[4];
#pragma unroll
    for (int cc = 0; cc < 4; ++cc) {
      kf[cc] = *(const f16x8*)(kb + (size_t)(kbase + cc * 16 + l15) * 256);
      va[cc] = *(const f16x4*)(v0p + kbase + cc * 16);
      vb[cc] = *(const f16x4*)(v1p + kbase + cc * 16);
    }
    // ---- pass A: QK + fixup (both q-tiles per K chunk) ----
    f32x4 s0[4], s1[4];
    float lm0 = -1e30f, lm1 = -1e30f;
#pragma unroll
    for (int cc = 0; cc < 4; ++cc) {
      const int k0 = kbase + cc * 16;
      f32x4 S0 = __builtin_amdgcn_mfma_f32_16x16x32_f16(
          kf[cc], qf0, (f32x4){0.f,0.f,0.f,0.f}, 0, 0, 0);
      f32x4 S1 = __builtin_amdgcn_mfma_f32_16x16x32_f16(
          kf[cc], qf1, (f32x4){0.f,0.f,0.f,0.f}, 0, 0, 0);
      const float ry0 = sry[l15][k0 >> 6];
      const float ry1 = sry[16 + l15][k0 >> 6];
      const float4 rx0 = *(const float4*)&srx[l15][(k0 & 63) + g * 4];
      const float4 rx1 = *(const float4*)&srx[16 + l15][(k0 & 63) + g * 4];
      const float4 sm = *(const float4*)&smask[k0 + g * 4];
      s0[cc][0] = fmaf(S0[0], L2E, rx0.x + sm.x + ry0);
      s0[cc][1] = fmaf(S0[1], L2E, rx0.y + sm.y + ry0);
      s0[cc][2] = fmaf(S0[2], L2E, rx0.z + sm.z + ry0);
      s0[cc][3] = fmaf(S0[3], L2E, rx0.w + sm.w + ry0);
      s1[cc][0] = fmaf(S1[0], L2E, rx1.x + sm.x + ry1);
      s1[cc][1] = fmaf(S1[1], L2E, rx1.y + sm.y + ry1);
      s1[cc][2] = fmaf(S1[2], L2E, rx1.z + sm.z + ry1);
      s1[cc][3] = fmaf(S1[3], L2E, rx1.w + sm.w + ry1);
      lm0 = fmaxf(lm0, fmaxf(fmaxf(s0[cc][0], s0[cc][1]), fmaxf(s0[cc][2], s0[cc][3])));
      lm1 = fmaxf(lm1, fmaxf(fmaxf(s1[cc][0], s1[cc][1]), fmaxf(s1[cc][2], s1[cc][3])));
    }
    lm0 = fmaxf(lm0, __shfl_xor(lm0, 16));
    lm0 = fmaxf(lm0, __shfl_xor(lm0, 32));
    lm1 = fmaxf(lm1, __shfl_xor(lm1, 16));
    lm1 = fmaxf(lm1, __shfl_xor(lm1, 32));
    const float mn0 = fmaxf(mrun0, lm0);
    const float mn1 = fmaxf(mrun1, lm1);
    const float f0 = exp2f(mrun0 - mn0);
    const float f1 = exp2f(mrun1 - mn1);
    mrun0 = mn0; mrun1 = mn1;
    lacc0 *= f0; lacc1 *= f1;
#pragma unroll
    for (int r = 0; r < 4; ++r) {
      O00[r] *= f0; O01[r] *= f0;
      O10[r] *= f1; O11[r] *= f1;
    }
    // ---- pass B: exp2 + PV ----
#pragma unroll
    for (int cc = 0; cc < 4; ++cc) {
      f16x4 pf0, pf1;
#pragma unroll
      for (int r = 0; r < 4; ++r) {
        const float p0 = exp2f(s0[cc][r] - mrun0);
        const float p1 = exp2f(s1[cc][r] - mrun1);
        lacc0 += p0; lacc1 += p1;
        pf0[r] = (f16)p0; pf1[r] = (f16)p1;
      }
      O00 = __builtin_amdgcn_mfma_f32_16x16x16f16(va[cc], pf0, O00, 0, 0, 0);
      O01 = __builtin_amdgcn_mfma_f32_16x16x16f16(vb[cc], pf0, O01, 0, 0, 0);
      O10 = __builtin_amdgcn_mfma_f32_16x16x16f16(va[cc], pf1, O10, 0, 0, 0);
      O11 = __builtin_amdgcn_mfma_f32_16x16x16f16(vb[cc], pf1, O11, 0, 0, 0);
    }
  }

  lacc0 += __shfl_xor(lacc0, 16); lacc0 += __shfl_xor(lacc0, 32);
  lacc1 += __shfl_xor(lacc1, 16); lacc1 += __shfl_xor(lacc1, 32);

  if (kh > 0) {
#pragma unroll
    for (int r = 0; r < 4; ++r) {
      mO[kh - 1][0][r][lane]     = O00[r];
      mO[kh - 1][0][4 + r][lane] = O01[r];
      mO[kh - 1][1][r][lane]     = O10[r];
      mO[kh - 1][1][4 + r][lane] = O11[r];
    }
    if (lane < 16) {
      mlm[kh - 1][lane]      = mrun0;
      mlm[kh - 1][16 + lane] = mrun1;
      mll[kh - 1][lane]      = lacc0;
      mll[kh - 1][16 + lane] = lacc1;
    }
  }
  __syncthreads();
  if (kh == 0) {
#pragma unroll
    for (int qt = 0; qt < 2; ++qt) {
      const float mr = qt ? mrun1 : mrun0;
      const float la = qt ? lacc1 : lacc0;
      const f32x4 Oa = qt ? O10 : O00;
      const f32x4 Ob = qt ? O11 : O01;
      float ms = mr;
#pragma unroll
      for (int w = 0; w < 7; ++w) ms = fmaxf(ms, mlm[w][qt * 16 + l15]);
      const float fme = exp2f(mr - ms);
      float lt = la * fme;
      float fw[7];
#pragma unroll
      for (int w = 0; w < 7; ++w) {
        fw[w] = exp2f(mlm[w][qt * 16 + l15] - ms);
        lt += mll[w][qt * 16 + l15] * fw[w];
      }
      const float rl = 1.0f / lt;
      const int qrow = qt ? qrow1 : qrow0;
      if (qrow < NQ_) {
        f16* xr = X + (size_t)(b * NQ_ + qrow) * 256 + h * 32;
        f16x4 p0, p1;
#pragma unroll
        for (int r = 0; r < 4; ++r) {
          float o0 = Oa[r] * fme, o1 = Ob[r] * fme;
#pragma unroll
          for (int w = 0; w < 7; ++w) {
            o0 += mO[w][qt][r][lane] * fw[w];
            o1 += mO[w][qt][4 + r][lane] * fw[w];
          }
          p0[r] = (f16)(o0 * rl);
          p1[r] = (f16)(o1 * rl);
        }
        *(f16x4*)(xr + g * 4) = p0;
        *(f16x4*)(xr + 16 + g * 4) = p1;
      }
    }
  }
}

// ---------------------------------------------------------------------------
extern "C" void kernel_launch(void* const* d_in, const int* in_sizes, int n_in,
                              void* d_out, int out_size, void* d_ws, size_t ws_size,
                              hipStream_t stream)
{
  const float* query  = (const float*)d_in[0];
  const float* refpts = (const float*)d_in[1];
  const float* kin    = (const float*)d_in[2];
  const float* vin    = (const float*)d_in[3];
  const int*   mask   = (const int*)d_in[5];
  const float* Wq = (const float*)d_in[6];
  const float* bq = (const float*)d_in[7];
  const float* Wk = (const float*)d_in[8];
  const float* bk = (const float*)d_in[9];
  const float* Wv = (const float*)d_in[10];
  const float* bv = (const float*)d_in[11];
  const float* Wp = (const float*)d_in[12];
  const float* bp = (const float*)d_in[13];
  const float* W1x = (const float*)d_in[14];
  const float* b1x = (const float*)d_in[15];
  const float* W2x = (const float*)d_in[16];
  const float* W1y = (const float*)d_in[17];
  const float* b1y = (const float*)d_in[18];
  const float* W2y = (const float*)d_in[19];

  char* wsb = (char*)d_ws;
  f16*   Qf  = (f16*)(wsb);                 // 1216*256 f16   = 622592 B
  f16*   Kf  = (f16*)(wsb + 622592);        // 4*4096*256 f16 = 8388608 B
  f16*   Vtf = (f16*)(wsb + 9011200);       // 4*256*4096 f16 = 8388608 B
  float* rpx = (float*)(wsb + 17399808);    // 4*300*512 f32  = 2457600 B
  float* rpy = (float*)(wsb + 19857408);    // 2457600 B
  f16*   X   = (f16*)(wsb + 22315008);      // 1216*256 f16   = 622592 B
  f16*   WT  = (f16*)(wsb + 22937600);      // 4*256*256 f16  = 524288 B

  const float scale = 0.17677669529663687f;  // 32^-0.5

  hipLaunchKernelGGL(prep_wt, dim3(4, 4, 4), dim3(256), 0, stream,
                     Wq, Wk, Wv, Wp, WT, scale);
  hipLaunchKernelGGL(rpe_kernel, dim3(B_ * NQ_, 2), dim3(256), 0, stream,
                     refpts, W1x, b1x, W2x, W1y, b1y, W2y, rpx, rpy);
  hipLaunchKernelGGL(proj_qkv, dim3(4, 256, 3), dim3(256), 0, stream,
                     query, kin, vin, WT, bq, bk, bv, Qf, Kf, Vtf, scale);
  hipLaunchKernelGGL(attn_mfma, dim3(B_ * H_ * 10), dim3(512), 0, stream,
                     Qf, Kf, Vtf, rpx, rpy, mask, X);
  hipLaunchKernelGGL(gemm_out, dim3(4, 19), dim3(256), 0, stream,
                     X, WT, bp, (float*)d_out);
}